// Round 21
// baseline (112.205 us; speedup 1.0000x reference)
//
#include <hip/hip_runtime.h>
#include <hip/hip_bf16.h>
#include <math.h>

// Problem constants
constexpr int B  = 2;
constexpr int C  = 64;
constexpr int H  = 128;
constexpr int W  = 128;
constexpr int O  = 64;
constexpr int DG = 8;
constexpr int K  = 3;
constexpr int KK = K * K;           // 9
constexpr int HW = H * W;           // 16384
constexpr int CG = C / DG;          // 8
constexpr int OM_C  = 3 * DG * KK;  // 216
constexpr int OFF_C = 2 * DG * KK;  // 144
constexpr int MSK_C = DG * KK;      // 72
constexpr float MRM = 10.0f;

typedef unsigned short u16;
typedef short bfx8 __attribute__((ext_vector_type(8)));   // 8 bf16 (4 VGPRs)
typedef float fx4 __attribute__((ext_vector_type(4)));    // MFMA accumulator

// Sizes
constexpr int X0T_N  = B * C * HW;      // 2097152 floats (x0 interleaved)
constexpr int WB2_STEP = 7168;          // u16 per (t,chunk) wh slab (14 KB)
constexpr int WB2_N  = 18 * WB2_STEP;   // 129024
constexpr int WD_N   = 8 * 3 * 4 * 2 * 512;  // 98304 u16 deform B-frags
constexpr int PW     = 130;             // padded width/height
constexpr int PADP   = PW * PW;         // 16900 padded pixels
constexpr int X1P_N  = B * PADP * C;    // u16 per buffer
constexpr int VKS    = 104;             // deform val k-stride

// tap deltas in padded-pixel u16 units
__device__ constexpr int TAPD[9] = {
    (-PW - 1) * 64, (-PW) * 64, (-PW + 1) * 64,
    (-1) * 64,      0,          (1) * 64,
    (PW - 1) * 64,  (PW) * 64,  (PW + 1) * 64
};

// fast transcendentals (single v_exp_f32 / v_rcp_f32; NaN-safe at +-inf)
__device__ __forceinline__ float fast_tanh(float x) {
    float e = __expf(2.0f * x);                       // inf for large x
    return 1.0f - 2.0f * __builtin_amdgcn_rcpf(e + 1.0f);
}
__device__ __forceinline__ float fast_sigmoid(float x) {
    return __builtin_amdgcn_rcpf(1.0f + __expf(-x));
}

// ---------------- prep1: wD (deform B-frags), padded x1 hi/lo, wB2 ---------
__global__ void __launch_bounds__(256)
prep1_kernel(const float* __restrict__ weight,
             const float* __restrict__ w_om,
             const float* __restrict__ x1,
             u16* __restrict__ wD,
             u16* __restrict__ x1p_hi,
             u16* __restrict__ x1p_lo,
             u16* __restrict__ wB2) {
    int idx = blockIdx.x * 256 + threadIdx.x;
    if (idx < WD_N) {
        int j    = idx & 7;
        int lane = (idx >> 3) & 63;
        int sel  = (idx >> 9) & 1;
        int nf   = (idx >> 10) & 3;
        int gks  = idx >> 12;           // 0..23
        int g = gks / 3, ks = gks - g * 3;
        int kg = ks * 32 + ((lane >> 4) << 3) + j;
        int oc = nf * 16 + (lane & 15);
        float v = 0.0f;
        if (kg < 72) {
            int i = kg >> 3, c = kg & 7;
            v = weight[oc * (C * KK) + (g * CG + c) * KK + i];
        }
        __hip_bfloat16 hb = __float2bfloat16(v);
        if (sel == 0) {
            wD[idx] = *(u16*)&hb;
        } else {
            float hf = __bfloat162float(hb);
            __hip_bfloat16 lb = __float2bfloat16(v - hf);
            wD[idx] = *(u16*)&lb;
        }
        return;
    }
    int i1 = idx - WD_N;
    if (i1 < B * HW) {   // transpose interior: x1 -> padded [p][ic] hi/lo
        int p = i1 & (HW - 1);
        int b = i1 >> 14;
        const float* xp = x1 + (size_t)b * C * HW + p;
        bfx8 vh[8], vl[8];
#pragma unroll
        for (int k = 0; k < 8; ++k) {
#pragma unroll
            for (int j = 0; j < 8; ++j) {
                float x = xp[(size_t)(k * 8 + j) * HW];
                __hip_bfloat16 hb = __float2bfloat16(x);
                float hf = __bfloat162float(hb);
                __hip_bfloat16 lb = __float2bfloat16(x - hf);
                vh[k][j] = *(short*)&hb;
                vl[k][j] = *(short*)&lb;
            }
        }
        int dpx = ((p >> 7) + 1) * PW + (p & (W - 1)) + 1;
        u16* dh = x1p_hi + ((size_t)b * PADP + dpx) * C;
        u16* dl = x1p_lo + ((size_t)b * PADP + dpx) * C;
#pragma unroll
        for (int k = 0; k < 8; ++k) {
            *(bfx8*)(dh + k * 8) = vh[k];
            *(bfx8*)(dl + k * 8) = vl[k];
        }
        return;
    }
    int i2 = i1 - B * HW;
    if (i2 < B * PADP) {  // zero the border pixels
        int b2 = i2 / PADP;
        int px = i2 - b2 * PADP;
        int rr = px / PW, cc = px - rr * PW;
        if (rr == 0 || rr == PW - 1 || cc == 0 || cc == PW - 1) {
            u16* zh = x1p_hi + ((size_t)b2 * PADP + px) * C;
            u16* zl = x1p_lo + ((size_t)b2 * PADP + px) * C;
            const bfx8 z = {0, 0, 0, 0, 0, 0, 0, 0};
#pragma unroll
            for (int k = 0; k < 8; ++k) {
                *(bfx8*)(zh + k * 8) = z;
                *(bfx8*)(zl + k * 8) = z;
            }
        }
        return;
    }
    int i3 = i2 - B * PADP;
    if (i3 < WB2_N) {
        // layout: [t 9][chunk 2][nfh 14][lane 64][j 8], wh only
        int step2 = i3 / WB2_STEP;
        int r     = i3 - step2 * WB2_STEP;
        int nfh  = r >> 9;
        int lane = (r >> 3) & 63;
        int j    = r & 7;
        int t = step2 >> 1, chunk = step2 & 1;
        int ic = chunk * 32 + ((lane >> 4) << 3) + j;
        int oc = (nfh << 4) + (lane & 15);
        float v = (oc < OM_C) ? w_om[oc * (C * KK) + ic * KK + t] : 0.0f;
        __hip_bfloat16 hb = __float2bfloat16(v);
        wB2[i3] = *(u16*)&hb;
    }
}

// ---------------- prep2: x0 channel-interleave ----------------
__global__ void __launch_bounds__(256)
prep2_kernel(const float* __restrict__ x0, float* __restrict__ x0T) {
    int idx = blockIdx.x * 256 + threadIdx.x;
    int p  = idx & (HW - 1);
    int ch = (idx >> 14) & (C - 1);
    int b  = idx >> 20;
    x0T[((size_t)((b * DG + (ch >> 3)) * HW + p) << 3) + (ch & 7)] = x0[idx];
}

// ---------------- conv_offset_mask: raw-output epilogue (R20 verbatim) -----
__global__ void __launch_bounds__(1024, 4)
conv_om_mfma_kernel(const u16* __restrict__ x1p_hi,
                    const u16* __restrict__ x1p_lo,
                    const u16* __restrict__ wB2,
                    const float* __restrict__ b_om,
                    float* __restrict__ rawoff,
                    float* __restrict__ rawmsk) {
    __shared__ __align__(16) u16 smem[2][2 * WB2_STEP];   // 57,344 B

    int bid  = blockIdx.x;                        // 256 blocks
    int work = ((bid & 7) << 5) + (bid >> 3);     // XCD-chunked
    int b    = work >> 7;
    int px0  = (work & 127) << 7;                 // 128-px tile

    int tid  = threadIdx.x;
    int lane = tid & 63;
    int wid  = tid >> 6;             // 0..15
    int kidc = wid & 1;              // ic-chunk
    int wcol = (wid >> 1) & 1;
    int wrow = wid >> 2;             // 0..3

    fx4 acc[2][7];
#pragma unroll
    for (int mf = 0; mf < 2; ++mf)
#pragma unroll
        for (int nf = 0; nf < 7; ++nf) acc[mf][nf] = fx4{0.f, 0.f, 0.f, 0.f};

    int pA    = px0 + wrow * 32 + (lane & 15);
    int klane = (lane >> 4) << 3;
    int base0 = (((pA >> 7) + 1) * PW + (pA & (W - 1)) + 1) * C + kidc * 32 + klane;
    int base1 = base0 + 16 * C;

    const u16* xh_b = x1p_hi + (size_t)b * PADP * C;
    const u16* xl_b = x1p_lo + (size_t)b * PADP * C;

    // staging: 14 waves x 2 insts cover 28 x 1KB slots (both chunks, wh only)
    bool stager = (wid < 14);
    int  soff0 = (wid * 2 + 0) * 512 + lane * 8;
    int  soff1 = (wid * 2 + 1) * 512 + lane * 8;

    if (stager) {
        __builtin_amdgcn_global_load_lds(
            (const __attribute__((address_space(1))) u16*)(wB2 + soff0),
            (__attribute__((address_space(3))) u16*)(&smem[0][0] + soff0), 16, 0, 0);
        __builtin_amdgcn_global_load_lds(
            (const __attribute__((address_space(1))) u16*)(wB2 + soff1),
            (__attribute__((address_space(3))) u16*)(&smem[0][0] + soff1), 16, 0, 0);
    }
    bfx8 ahc0 = *(const bfx8*)(xh_b + base0 + TAPD[0]);
    bfx8 ahc1 = *(const bfx8*)(xh_b + base1 + TAPD[0]);
    bfx8 alc0 = *(const bfx8*)(xl_b + base0 + TAPD[0]);
    bfx8 alc1 = *(const bfx8*)(xl_b + base1 + TAPD[0]);
    __syncthreads();

#pragma unroll
    for (int t = 0; t < 9; ++t) {
        bfx8 ahn0, ahn1, aln0, aln1;
        if (t < 8) {
            if (stager) {
                const u16* src = wB2 + (size_t)(t + 1) * 2 * WB2_STEP;
                u16* dst = &smem[(t + 1) & 1][0];
                __builtin_amdgcn_global_load_lds(
                    (const __attribute__((address_space(1))) u16*)(src + soff0),
                    (__attribute__((address_space(3))) u16*)(dst + soff0), 16, 0, 0);
                __builtin_amdgcn_global_load_lds(
                    (const __attribute__((address_space(1))) u16*)(src + soff1),
                    (__attribute__((address_space(3))) u16*)(dst + soff1), 16, 0, 0);
            }
            int d = TAPD[t + 1];
            ahn0 = *(const bfx8*)(xh_b + base0 + d);
            ahn1 = *(const bfx8*)(xh_b + base1 + d);
            aln0 = *(const bfx8*)(xl_b + base0 + d);
            aln1 = *(const bfx8*)(xl_b + base1 + d);
        }
        const u16* slab = &smem[t & 1][kidc * WB2_STEP];
#pragma unroll
        for (int nf = 0; nf < 7; ++nf) {
            bfx8 bh = *(const bfx8*)(slab + ((wcol * 7 + nf) << 9) + (lane << 3));
            acc[0][nf] = __builtin_amdgcn_mfma_f32_16x16x32_bf16(ahc0, bh, acc[0][nf], 0, 0, 0);
            acc[0][nf] = __builtin_amdgcn_mfma_f32_16x16x32_bf16(alc0, bh, acc[0][nf], 0, 0, 0);
            acc[1][nf] = __builtin_amdgcn_mfma_f32_16x16x32_bf16(ahc1, bh, acc[1][nf], 0, 0, 0);
            acc[1][nf] = __builtin_amdgcn_mfma_f32_16x16x32_bf16(alc1, bh, acc[1][nf], 0, 0, 0);
        }
        __syncthreads();
        if (t < 8) {
            ahc0 = ahn0; ahc1 = ahn1; alc0 = aln0; alc1 = aln1;
        }
    }

    // kid reduction via LDS, 2 rounds over wcol; full 128-B line stores.
    fx4* red = (fx4*)&smem[0][0];
#pragma unroll
    for (int rc = 0; rc < 2; ++rc) {
        if (kidc == 1 && wcol == rc) {
#pragma unroll
            for (int mf = 0; mf < 2; ++mf)
#pragma unroll
                for (int nf = 0; nf < 7; ++nf)
                    red[(((wrow << 1) + mf) * 7 + nf) * 64 + lane] = acc[mf][nf];
        }
        __syncthreads();
        if (kidc == 0 && wcol == rc) {
#pragma unroll
            for (int nf = 0; nf < 7; ++nf) {
#pragma unroll
                for (int mf = 0; mf < 2; ++mf) {
                    fx4 v = acc[mf][nf] + red[(((wrow << 1) + mf) * 7 + nf) * 64 + lane];
                    int oc  = rc * 112 + nf * 16 + (lane & 15);
                    int pix = px0 + wrow * 32 + mf * 16 + ((lane >> 4) << 2);
                    if (oc < OM_C) {
                        float bb = b_om[oc];
                        float4 r;
                        r.x = v[0] + bb; r.y = v[1] + bb;
                        r.z = v[2] + bb; r.w = v[3] + bb;
                        if (oc < OFF_C) {
                            *(float4*)&rawoff[(size_t)(b * OFF_C + oc) * HW + pix] = r;
                        } else {
                            *(float4*)&rawmsk[(size_t)(b * MSK_C + oc - OFF_C) * HW + pix] = r;
                        }
                    }
                }
            }
        }
        __syncthreads();
    }
}

// ---------------- deform conv via MFMA + fused transform (fast path) ------
// R20 structure + (1) fast tanh/sigmoid (v_exp+v_rcp instead of libm chain),
// (2) 6 blocks/CU (LDS 26.6KB x 6 = 159.7KB fits; VGPR 52 <= 85 cap).
__global__ void __launch_bounds__(256, 6)
deform_mfma_kernel(const float* __restrict__ x0T,
                   const float* __restrict__ rawoff,
                   const float* __restrict__ rawmsk,
                   const float* __restrict__ pre_offset,
                   const float* __restrict__ pre_sim,
                   const u16* __restrict__ wD,
                   const float* __restrict__ bias,
                   float* __restrict__ out) {
    __shared__ __align__(16) u16 val[2][2][32][VKS];   // 26,624 B

    int bid  = blockIdx.x;                        // 1024 blocks
    int work = ((bid & 7) << 7) + (bid >> 3);     // XCD-chunked
    int b    = work >> 9;
    int px0  = (work & 511) << 5;

    int tid  = threadIdx.x;
    int lane = tid & 63;
    int nf   = tid >> 6;          // wave id = N-frag 0..3

    {
        const bfx8 z = {0, 0, 0, 0, 0, 0, 0, 0};
#pragma unroll
        for (int zz = 0; zz < 2; ++zz) {
            int zc = zz * 256 + tid;           // 0..511
            int sub  = zc & 3;
            int rest = zc >> 2;                // 0..127
            int p    = rest & 31;
            int grel = (rest >> 5) & 1;
            int hl   = rest >> 6;
            *(bfx8*)&val[hl][grel][p][72 + sub * 8] = z;
        }
    }

    fx4 acc[2];
    acc[0] = fx4{0.f, 0.f, 0.f, 0.f};
    acc[1] = fx4{0.f, 0.f, 0.f, 0.f};

    for (int r = 0; r < 4; ++r) {
        __syncthreads();
#pragma unroll
        for (int rep = 0; rep < 3; ++rep) {
            int s = rep * 256 + tid;
            if (s < 576) {
                int p    = s & 31;
                int rest = s >> 5;            // 0..17
                int grel = rest / 9;
                int i    = rest - grel * 9;
                int g    = 2 * r + grel;
                int gi   = g * 9 + i;
                int gp   = px0 + p;
                int h = gp >> 7, w = gp & (W - 1);

                size_t oyi = (size_t)(b * OFF_C + 2 * gi) * HW + gp;
                size_t oxi = (size_t)(b * OFF_C + 2 * gi + 1) * HW + gp;
                size_t mii = (size_t)(b * MSK_C + gi) * HW + gp;
                float offy = MRM * fast_tanh(rawoff[oyi]) + pre_offset[oyi];
                float offx = MRM * fast_tanh(rawoff[oxi]) + pre_offset[oxi];
                float m    = fast_sigmoid(rawmsk[mii] * pre_sim[mii]);

                float py = offy + (float)(h - 1 + i / 3);
                float px = offx + (float)(w - 1 + i % 3);
                float fy = floorf(py), fx = floorf(px);
                float ly = py - fy, lx = px - fx;
                float hy = 1.0f - ly, hx = 1.0f - lx;
                int y0 = (int)fy, x0i = (int)fx;
                int y1 = y0 + 1, x1i = x0i + 1;
                bool vy0 = (y0 >= 0) && (y0 < H);
                bool vy1 = (y1 >= 0) && (y1 < H);
                bool vx0 = (x0i >= 0) && (x0i < W);
                bool vx1 = (x1i >= 0) && (x1i < W);
                int cy0 = min(max(y0, 0), H - 1), cy1 = min(max(y1, 0), H - 1);
                int cx0 = min(max(x0i, 0), W - 1), cx1 = min(max(x1i, 0), W - 1);
                float w00 = hy * hx * ((vy0 && vx0) ? 1.0f : 0.0f) * m;
                float w01 = hy * lx * ((vy0 && vx1) ? 1.0f : 0.0f) * m;
                float w10 = ly * hx * ((vy1 && vx0) ? 1.0f : 0.0f) * m;
                float w11 = ly * lx * ((vy1 && vx1) ? 1.0f : 0.0f) * m;
                int i00 = cy0 * W + cx0, i01 = cy0 * W + cx1;
                int i10 = cy1 * W + cx0, i11 = cy1 * W + cx1;

                const float* xg = x0T + ((size_t)(b * DG + g) * HW) * CG;
                const float4* A  = (const float4*)(xg + (size_t)i00 * CG);
                const float4* Bc = (const float4*)(xg + (size_t)i01 * CG);
                const float4* Cc = (const float4*)(xg + (size_t)i10 * CG);
                const float4* Dc = (const float4*)(xg + (size_t)i11 * CG);
                float4 a0 = A[0],  a1 = A[1];
                float4 b0 = Bc[0], b1 = Bc[1];
                float4 c0 = Cc[0], c1 = Cc[1];
                float4 d0 = Dc[0], d1 = Dc[1];

                float v[CG];
                v[0] = w00 * a0.x + w01 * b0.x + w10 * c0.x + w11 * d0.x;
                v[1] = w00 * a0.y + w01 * b0.y + w10 * c0.y + w11 * d0.y;
                v[2] = w00 * a0.z + w01 * b0.z + w10 * c0.z + w11 * d0.z;
                v[3] = w00 * a0.w + w01 * b0.w + w10 * c0.w + w11 * d0.w;
                v[4] = w00 * a1.x + w01 * b1.x + w10 * c1.x + w11 * d1.x;
                v[5] = w00 * a1.y + w01 * b1.y + w10 * c1.y + w11 * d1.y;
                v[6] = w00 * a1.z + w01 * b1.z + w10 * c1.z + w11 * d1.z;
                v[7] = w00 * a1.w + w01 * b1.w + w10 * c1.w + w11 * d1.w;

                bfx8 vh, vl;
#pragma unroll
                for (int c = 0; c < CG; ++c) {
                    __hip_bfloat16 hb = __float2bfloat16(v[c]);
                    float hf = __bfloat162float(hb);
                    __hip_bfloat16 lb = __float2bfloat16(v[c] - hf);
                    vh[c] = *(short*)&hb;
                    vl[c] = *(short*)&lb;
                }
                *(bfx8*)&val[0][grel][p][i * 8] = vh;
                *(bfx8*)&val[1][grel][p][i * 8] = vl;
            }
        }
        __syncthreads();
#pragma unroll
        for (int ks = 0; ks < 6; ++ks) {
            int grel = ks / 3;
            int ksl  = ks - grel * 3;
            int g    = 2 * r + grel;
            int kk   = ksl * 32 + ((lane >> 4) << 3);

            const u16* bp = wD + (size_t)(((g * 3 + ksl) * 4 + nf) * 2) * 512 + lane * 8;
            bfx8 bh = *(const bfx8*)bp;
            bfx8 bl = *(const bfx8*)(bp + 512);

            int row0 = lane & 15;
            bfx8 a0h = *(const bfx8*)&val[0][grel][row0][kk];
            bfx8 a0l = *(const bfx8*)&val[1][grel][row0][kk];
            bfx8 a1h = *(const bfx8*)&val[0][grel][row0 + 16][kk];
            bfx8 a1l = *(const bfx8*)&val[1][grel][row0 + 16][kk];

            acc[0] = __builtin_amdgcn_mfma_f32_16x16x32_bf16(a0h, bh, acc[0], 0, 0, 0);
            acc[0] = __builtin_amdgcn_mfma_f32_16x16x32_bf16(a0l, bh, acc[0], 0, 0, 0);
            acc[0] = __builtin_amdgcn_mfma_f32_16x16x32_bf16(a0h, bl, acc[0], 0, 0, 0);
            acc[1] = __builtin_amdgcn_mfma_f32_16x16x32_bf16(a1h, bh, acc[1], 0, 0, 0);
            acc[1] = __builtin_amdgcn_mfma_f32_16x16x32_bf16(a1l, bh, acc[1], 0, 0, 0);
            acc[1] = __builtin_amdgcn_mfma_f32_16x16x32_bf16(a1h, bl, acc[1], 0, 0, 0);
        }
    }

    __syncthreads();
    float* trans = (float*)&val[0][0][0][0];   // 64*36*4 = 9216 B
#pragma unroll
    for (int t = 0; t < 2; ++t) {
        int oc = nf * 16 + (lane & 15);
        int p4 = t * 16 + ((lane >> 4) << 2);
        *(fx4*)&trans[oc * 36 + p4] = acc[t];
    }
    __syncthreads();
#pragma unroll
    for (int t = 0; t < 2; ++t) {
        int f  = t * 256 + tid;           // 0..511
        int oc = f >> 3;                  // 0..63
        int c4 = f & 7;
        float4 v = *(float4*)&trans[oc * 36 + c4 * 4];
        float bb = bias[oc];
        v.x += bb; v.y += bb; v.z += bb; v.w += bb;
        *(float4*)&out[((size_t)b * O + oc) * HW + px0 + c4 * 4] = v;
    }
}

// ---------------- Launch ----------------
extern "C" void kernel_launch(void* const* d_in, const int* in_sizes, int n_in,
                              void* d_out, int out_size, void* d_ws, size_t ws_size,
                              hipStream_t stream) {
    (void)in_sizes; (void)n_in; (void)out_size; (void)ws_size;
    const float* x0         = (const float*)d_in[0];
    const float* x1         = (const float*)d_in[1];
    const float* pre_offset = (const float*)d_in[2];
    const float* pre_sim    = (const float*)d_in[3];
    const float* weight     = (const float*)d_in[4];
    const float* bias       = (const float*)d_in[5];
    const float* w_om       = (const float*)d_in[6];
    const float* b_om       = (const float*)d_in[7];
    float* out = (float*)d_out;

    // ws layout: rawoff | rawmsk | xbuf(x1p_hi,x1p_lo / x0T union) | wB2 | wD
    float* rawoff = (float*)d_ws;                       // B*OFF_C*HW floats
    float* rawmsk = rawoff + (size_t)B * OFF_C * HW;    // B*MSK_C*HW floats
    float* xbuf   = rawmsk + (size_t)B * MSK_C * HW;
    u16*   x1p_hi = (u16*)xbuf;                         // X1P_N u16
    u16*   x1p_lo = x1p_hi + (size_t)X1P_N;             // X1P_N u16
    float* x0T    = xbuf;                               // aliases x1p (after conv)
    u16*   wB2    = x1p_lo + (size_t)X1P_N;             // WB2_N u16
    u16*   wD     = wB2 + (size_t)WB2_N;                // WD_N u16

    {
        int total = WD_N + B * HW + B * PADP + WB2_N;   // 293896
        prep1_kernel<<<(total + 255) / 256, 256, 0, stream>>>(
            weight, w_om, x1, wD, x1p_hi, x1p_lo, wB2);
    }
    {
        conv_om_mfma_kernel<<<256, 1024, 0, stream>>>(
            x1p_hi, x1p_lo, wB2, b_om, rawoff, rawmsk);
    }
    {
        prep2_kernel<<<X0T_N / 256, 256, 0, stream>>>(x0, x0T);
    }
    {
        deform_mfma_kernel<<<1024, 256, 0, stream>>>(
            x0T, rawoff, rawmsk, pre_offset, pre_sim, wD, bias, out);
    }
}

// Round 22
// 96.132 us; speedup vs baseline: 1.1672x; 1.1672x over previous
//
#include <hip/hip_runtime.h>
#include <hip/hip_bf16.h>
#include <math.h>

// Problem constants
constexpr int B  = 2;
constexpr int C  = 64;
constexpr int H  = 128;
constexpr int W  = 128;
constexpr int O  = 64;
constexpr int DG = 8;
constexpr int K  = 3;
constexpr int KK = K * K;           // 9
constexpr int HW = H * W;           // 16384
constexpr int CG = C / DG;          // 8
constexpr int OM_C  = 3 * DG * KK;  // 216
constexpr int OFF_C = 2 * DG * KK;  // 144
constexpr int MSK_C = DG * KK;      // 72
constexpr float MRM = 10.0f;

typedef unsigned short u16;
typedef short bfx8 __attribute__((ext_vector_type(8)));   // 8 bf16 (4 VGPRs)
typedef float fx4 __attribute__((ext_vector_type(4)));    // MFMA accumulator

// Sizes
constexpr int X0T_N  = B * C * HW;      // 2097152 floats (x0 interleaved)
constexpr int WB2_STEP = 7168;          // u16 per (t,chunk) wh slab (14 KB)
constexpr int WB2_N  = 18 * WB2_STEP;   // 129024
constexpr int WD_N   = 8 * 3 * 4 * 2 * 512;  // 98304 u16 deform B-frags
constexpr int PW     = 130;             // padded width/height
constexpr int PADP   = PW * PW;         // 16900 padded pixels
constexpr int X1P_N  = B * PADP * C;    // u16 per buffer
constexpr int VKS    = 104;             // deform val k-stride

// tap deltas in padded-pixel u16 units
__device__ constexpr int TAPD[9] = {
    (-PW - 1) * 64, (-PW) * 64, (-PW + 1) * 64,
    (-1) * 64,      0,          (1) * 64,
    (PW - 1) * 64,  (PW) * 64,  (PW + 1) * 64
};

// fast transcendentals (single v_exp_f32 / v_rcp_f32; NaN-safe at +-inf)
__device__ __forceinline__ float fast_tanh(float x) {
    float e = __expf(2.0f * x);                       // inf for large x
    return 1.0f - 2.0f * __builtin_amdgcn_rcpf(e + 1.0f);
}
__device__ __forceinline__ float fast_sigmoid(float x) {
    return __builtin_amdgcn_rcpf(1.0f + __expf(-x));
}

// ---------------- prep1: wD (deform B-frags), padded x1 hi/lo, wB2 ---------
__global__ void __launch_bounds__(256)
prep1_kernel(const float* __restrict__ weight,
             const float* __restrict__ w_om,
             const float* __restrict__ x1,
             u16* __restrict__ wD,
             u16* __restrict__ x1p_hi,
             u16* __restrict__ x1p_lo,
             u16* __restrict__ wB2) {
    int idx = blockIdx.x * 256 + threadIdx.x;
    if (idx < WD_N) {
        int j    = idx & 7;
        int lane = (idx >> 3) & 63;
        int sel  = (idx >> 9) & 1;
        int nf   = (idx >> 10) & 3;
        int gks  = idx >> 12;           // 0..23
        int g = gks / 3, ks = gks - g * 3;
        int kg = ks * 32 + ((lane >> 4) << 3) + j;
        int oc = nf * 16 + (lane & 15);
        float v = 0.0f;
        if (kg < 72) {
            int i = kg >> 3, c = kg & 7;
            v = weight[oc * (C * KK) + (g * CG + c) * KK + i];
        }
        __hip_bfloat16 hb = __float2bfloat16(v);
        if (sel == 0) {
            wD[idx] = *(u16*)&hb;
        } else {
            float hf = __bfloat162float(hb);
            __hip_bfloat16 lb = __float2bfloat16(v - hf);
            wD[idx] = *(u16*)&lb;
        }
        return;
    }
    int i1 = idx - WD_N;
    if (i1 < B * HW) {   // transpose interior: x1 -> padded [p][ic] hi/lo
        int p = i1 & (HW - 1);
        int b = i1 >> 14;
        const float* xp = x1 + (size_t)b * C * HW + p;
        bfx8 vh[8], vl[8];
#pragma unroll
        for (int k = 0; k < 8; ++k) {
#pragma unroll
            for (int j = 0; j < 8; ++j) {
                float x = xp[(size_t)(k * 8 + j) * HW];
                __hip_bfloat16 hb = __float2bfloat16(x);
                float hf = __bfloat162float(hb);
                __hip_bfloat16 lb = __float2bfloat16(x - hf);
                vh[k][j] = *(short*)&hb;
                vl[k][j] = *(short*)&lb;
            }
        }
        int dpx = ((p >> 7) + 1) * PW + (p & (W - 1)) + 1;
        u16* dh = x1p_hi + ((size_t)b * PADP + dpx) * C;
        u16* dl = x1p_lo + ((size_t)b * PADP + dpx) * C;
#pragma unroll
        for (int k = 0; k < 8; ++k) {
            *(bfx8*)(dh + k * 8) = vh[k];
            *(bfx8*)(dl + k * 8) = vl[k];
        }
        return;
    }
    int i2 = i1 - B * HW;
    if (i2 < B * PADP) {  // zero the border pixels
        int b2 = i2 / PADP;
        int px = i2 - b2 * PADP;
        int rr = px / PW, cc = px - rr * PW;
        if (rr == 0 || rr == PW - 1 || cc == 0 || cc == PW - 1) {
            u16* zh = x1p_hi + ((size_t)b2 * PADP + px) * C;
            u16* zl = x1p_lo + ((size_t)b2 * PADP + px) * C;
            const bfx8 z = {0, 0, 0, 0, 0, 0, 0, 0};
#pragma unroll
            for (int k = 0; k < 8; ++k) {
                *(bfx8*)(zh + k * 8) = z;
                *(bfx8*)(zl + k * 8) = z;
            }
        }
        return;
    }
    int i3 = i2 - B * PADP;
    if (i3 < WB2_N) {
        // layout: [t 9][chunk 2][nfh 14][lane 64][j 8], wh only
        int step2 = i3 / WB2_STEP;
        int r     = i3 - step2 * WB2_STEP;
        int nfh  = r >> 9;
        int lane = (r >> 3) & 63;
        int j    = r & 7;
        int t = step2 >> 1, chunk = step2 & 1;
        int ic = chunk * 32 + ((lane >> 4) << 3) + j;
        int oc = (nfh << 4) + (lane & 15);
        float v = (oc < OM_C) ? w_om[oc * (C * KK) + ic * KK + t] : 0.0f;
        __hip_bfloat16 hb = __float2bfloat16(v);
        wB2[i3] = *(u16*)&hb;
    }
}

// ---------------- prep2: x0 channel-interleave ----------------
__global__ void __launch_bounds__(256)
prep2_kernel(const float* __restrict__ x0, float* __restrict__ x0T) {
    int idx = blockIdx.x * 256 + threadIdx.x;
    int p  = idx & (HW - 1);
    int ch = (idx >> 14) & (C - 1);
    int b  = idx >> 20;
    x0T[((size_t)((b * DG + (ch >> 3)) * HW + p) << 3) + (ch & 7)] = x0[idx];
}

// ---------------- conv_offset_mask: raw-output epilogue (R20 verbatim) -----
__global__ void __launch_bounds__(1024, 4)
conv_om_mfma_kernel(const u16* __restrict__ x1p_hi,
                    const u16* __restrict__ x1p_lo,
                    const u16* __restrict__ wB2,
                    const float* __restrict__ b_om,
                    float* __restrict__ rawoff,
                    float* __restrict__ rawmsk) {
    __shared__ __align__(16) u16 smem[2][2 * WB2_STEP];   // 57,344 B

    int bid  = blockIdx.x;                        // 256 blocks
    int work = ((bid & 7) << 5) + (bid >> 3);     // XCD-chunked
    int b    = work >> 7;
    int px0  = (work & 127) << 7;                 // 128-px tile

    int tid  = threadIdx.x;
    int lane = tid & 63;
    int wid  = tid >> 6;             // 0..15
    int kidc = wid & 1;              // ic-chunk
    int wcol = (wid >> 1) & 1;
    int wrow = wid >> 2;             // 0..3

    fx4 acc[2][7];
#pragma unroll
    for (int mf = 0; mf < 2; ++mf)
#pragma unroll
        for (int nf = 0; nf < 7; ++nf) acc[mf][nf] = fx4{0.f, 0.f, 0.f, 0.f};

    int pA    = px0 + wrow * 32 + (lane & 15);
    int klane = (lane >> 4) << 3;
    int base0 = (((pA >> 7) + 1) * PW + (pA & (W - 1)) + 1) * C + kidc * 32 + klane;
    int base1 = base0 + 16 * C;

    const u16* xh_b = x1p_hi + (size_t)b * PADP * C;
    const u16* xl_b = x1p_lo + (size_t)b * PADP * C;

    // staging: 14 waves x 2 insts cover 28 x 1KB slots (both chunks, wh only)
    bool stager = (wid < 14);
    int  soff0 = (wid * 2 + 0) * 512 + lane * 8;
    int  soff1 = (wid * 2 + 1) * 512 + lane * 8;

    if (stager) {
        __builtin_amdgcn_global_load_lds(
            (const __attribute__((address_space(1))) u16*)(wB2 + soff0),
            (__attribute__((address_space(3))) u16*)(&smem[0][0] + soff0), 16, 0, 0);
        __builtin_amdgcn_global_load_lds(
            (const __attribute__((address_space(1))) u16*)(wB2 + soff1),
            (__attribute__((address_space(3))) u16*)(&smem[0][0] + soff1), 16, 0, 0);
    }
    bfx8 ahc0 = *(const bfx8*)(xh_b + base0 + TAPD[0]);
    bfx8 ahc1 = *(const bfx8*)(xh_b + base1 + TAPD[0]);
    bfx8 alc0 = *(const bfx8*)(xl_b + base0 + TAPD[0]);
    bfx8 alc1 = *(const bfx8*)(xl_b + base1 + TAPD[0]);
    __syncthreads();

#pragma unroll
    for (int t = 0; t < 9; ++t) {
        bfx8 ahn0, ahn1, aln0, aln1;
        if (t < 8) {
            if (stager) {
                const u16* src = wB2 + (size_t)(t + 1) * 2 * WB2_STEP;
                u16* dst = &smem[(t + 1) & 1][0];
                __builtin_amdgcn_global_load_lds(
                    (const __attribute__((address_space(1))) u16*)(src + soff0),
                    (__attribute__((address_space(3))) u16*)(dst + soff0), 16, 0, 0);
                __builtin_amdgcn_global_load_lds(
                    (const __attribute__((address_space(1))) u16*)(src + soff1),
                    (__attribute__((address_space(3))) u16*)(dst + soff1), 16, 0, 0);
            }
            int d = TAPD[t + 1];
            ahn0 = *(const bfx8*)(xh_b + base0 + d);
            ahn1 = *(const bfx8*)(xh_b + base1 + d);
            aln0 = *(const bfx8*)(xl_b + base0 + d);
            aln1 = *(const bfx8*)(xl_b + base1 + d);
        }
        const u16* slab = &smem[t & 1][kidc * WB2_STEP];
#pragma unroll
        for (int nf = 0; nf < 7; ++nf) {
            bfx8 bh = *(const bfx8*)(slab + ((wcol * 7 + nf) << 9) + (lane << 3));
            acc[0][nf] = __builtin_amdgcn_mfma_f32_16x16x32_bf16(ahc0, bh, acc[0][nf], 0, 0, 0);
            acc[0][nf] = __builtin_amdgcn_mfma_f32_16x16x32_bf16(alc0, bh, acc[0][nf], 0, 0, 0);
            acc[1][nf] = __builtin_amdgcn_mfma_f32_16x16x32_bf16(ahc1, bh, acc[1][nf], 0, 0, 0);
            acc[1][nf] = __builtin_amdgcn_mfma_f32_16x16x32_bf16(alc1, bh, acc[1][nf], 0, 0, 0);
        }
        __syncthreads();
        if (t < 8) {
            ahc0 = ahn0; ahc1 = ahn1; alc0 = aln0; alc1 = aln1;
        }
    }

    // kid reduction via LDS, 2 rounds over wcol; full 128-B line stores.
    fx4* red = (fx4*)&smem[0][0];
#pragma unroll
    for (int rc = 0; rc < 2; ++rc) {
        if (kidc == 1 && wcol == rc) {
#pragma unroll
            for (int mf = 0; mf < 2; ++mf)
#pragma unroll
                for (int nf = 0; nf < 7; ++nf)
                    red[(((wrow << 1) + mf) * 7 + nf) * 64 + lane] = acc[mf][nf];
        }
        __syncthreads();
        if (kidc == 0 && wcol == rc) {
#pragma unroll
            for (int nf = 0; nf < 7; ++nf) {
#pragma unroll
                for (int mf = 0; mf < 2; ++mf) {
                    fx4 v = acc[mf][nf] + red[(((wrow << 1) + mf) * 7 + nf) * 64 + lane];
                    int oc  = rc * 112 + nf * 16 + (lane & 15);
                    int pix = px0 + wrow * 32 + mf * 16 + ((lane >> 4) << 2);
                    if (oc < OM_C) {
                        float bb = b_om[oc];
                        float4 r;
                        r.x = v[0] + bb; r.y = v[1] + bb;
                        r.z = v[2] + bb; r.w = v[3] + bb;
                        if (oc < OFF_C) {
                            *(float4*)&rawoff[(size_t)(b * OFF_C + oc) * HW + pix] = r;
                        } else {
                            *(float4*)&rawmsk[(size_t)(b * MSK_C + oc - OFF_C) * HW + pix] = r;
                        }
                    }
                }
            }
        }
        __syncthreads();
    }
}

// ---------------- deform conv via MFMA + fused transform ------------------
// R20 structure (launch_bounds(256,4), VGPR 52, zero spill) + fast
// tanh/sigmoid only. R21's (256,6) caused scratch spills (WRITE 8->56 MB).
__global__ void __launch_bounds__(256, 4)
deform_mfma_kernel(const float* __restrict__ x0T,
                   const float* __restrict__ rawoff,
                   const float* __restrict__ rawmsk,
                   const float* __restrict__ pre_offset,
                   const float* __restrict__ pre_sim,
                   const u16* __restrict__ wD,
                   const float* __restrict__ bias,
                   float* __restrict__ out) {
    __shared__ __align__(16) u16 val[2][2][32][VKS];   // 26,624 B

    int bid  = blockIdx.x;                        // 1024 blocks
    int work = ((bid & 7) << 7) + (bid >> 3);     // XCD-chunked
    int b    = work >> 9;
    int px0  = (work & 511) << 5;

    int tid  = threadIdx.x;
    int lane = tid & 63;
    int nf   = tid >> 6;          // wave id = N-frag 0..3

    {
        const bfx8 z = {0, 0, 0, 0, 0, 0, 0, 0};
#pragma unroll
        for (int zz = 0; zz < 2; ++zz) {
            int zc = zz * 256 + tid;           // 0..511
            int sub  = zc & 3;
            int rest = zc >> 2;                // 0..127
            int p    = rest & 31;
            int grel = (rest >> 5) & 1;
            int hl   = rest >> 6;
            *(bfx8*)&val[hl][grel][p][72 + sub * 8] = z;
        }
    }

    fx4 acc[2];
    acc[0] = fx4{0.f, 0.f, 0.f, 0.f};
    acc[1] = fx4{0.f, 0.f, 0.f, 0.f};

    for (int r = 0; r < 4; ++r) {
        __syncthreads();
#pragma unroll
        for (int rep = 0; rep < 3; ++rep) {
            int s = rep * 256 + tid;
            if (s < 576) {
                int p    = s & 31;
                int rest = s >> 5;            // 0..17
                int grel = rest / 9;
                int i    = rest - grel * 9;
                int g    = 2 * r + grel;
                int gi   = g * 9 + i;
                int gp   = px0 + p;
                int h = gp >> 7, w = gp & (W - 1);

                size_t oyi = (size_t)(b * OFF_C + 2 * gi) * HW + gp;
                size_t oxi = (size_t)(b * OFF_C + 2 * gi + 1) * HW + gp;
                size_t mii = (size_t)(b * MSK_C + gi) * HW + gp;
                float offy = MRM * fast_tanh(rawoff[oyi]) + pre_offset[oyi];
                float offx = MRM * fast_tanh(rawoff[oxi]) + pre_offset[oxi];
                float m    = fast_sigmoid(rawmsk[mii] * pre_sim[mii]);

                float py = offy + (float)(h - 1 + i / 3);
                float px = offx + (float)(w - 1 + i % 3);
                float fy = floorf(py), fx = floorf(px);
                float ly = py - fy, lx = px - fx;
                float hy = 1.0f - ly, hx = 1.0f - lx;
                int y0 = (int)fy, x0i = (int)fx;
                int y1 = y0 + 1, x1i = x0i + 1;
                bool vy0 = (y0 >= 0) && (y0 < H);
                bool vy1 = (y1 >= 0) && (y1 < H);
                bool vx0 = (x0i >= 0) && (x0i < W);
                bool vx1 = (x1i >= 0) && (x1i < W);
                int cy0 = min(max(y0, 0), H - 1), cy1 = min(max(y1, 0), H - 1);
                int cx0 = min(max(x0i, 0), W - 1), cx1 = min(max(x1i, 0), W - 1);
                float w00 = hy * hx * ((vy0 && vx0) ? 1.0f : 0.0f) * m;
                float w01 = hy * lx * ((vy0 && vx1) ? 1.0f : 0.0f) * m;
                float w10 = ly * hx * ((vy1 && vx0) ? 1.0f : 0.0f) * m;
                float w11 = ly * lx * ((vy1 && vx1) ? 1.0f : 0.0f) * m;
                int i00 = cy0 * W + cx0, i01 = cy0 * W + cx1;
                int i10 = cy1 * W + cx0, i11 = cy1 * W + cx1;

                const float* xg = x0T + ((size_t)(b * DG + g) * HW) * CG;
                const float4* A  = (const float4*)(xg + (size_t)i00 * CG);
                const float4* Bc = (const float4*)(xg + (size_t)i01 * CG);
                const float4* Cc = (const float4*)(xg + (size_t)i10 * CG);
                const float4* Dc = (const float4*)(xg + (size_t)i11 * CG);
                float4 a0 = A[0],  a1 = A[1];
                float4 b0 = Bc[0], b1 = Bc[1];
                float4 c0 = Cc[0], c1 = Cc[1];
                float4 d0 = Dc[0], d1 = Dc[1];

                float v[CG];
                v[0] = w00 * a0.x + w01 * b0.x + w10 * c0.x + w11 * d0.x;
                v[1] = w00 * a0.y + w01 * b0.y + w10 * c0.y + w11 * d0.y;
                v[2] = w00 * a0.z + w01 * b0.z + w10 * c0.z + w11 * d0.z;
                v[3] = w00 * a0.w + w01 * b0.w + w10 * c0.w + w11 * d0.w;
                v[4] = w00 * a1.x + w01 * b1.x + w10 * c1.x + w11 * d1.x;
                v[5] = w00 * a1.y + w01 * b1.y + w10 * c1.y + w11 * d1.y;
                v[6] = w00 * a1.z + w01 * b1.z + w10 * c1.z + w11 * d1.z;
                v[7] = w00 * a1.w + w01 * b1.w + w10 * c1.w + w11 * d1.w;

                bfx8 vh, vl;
#pragma unroll
                for (int c = 0; c < CG; ++c) {
                    __hip_bfloat16 hb = __float2bfloat16(v[c]);
                    float hf = __bfloat162float(hb);
                    __hip_bfloat16 lb = __float2bfloat16(v[c] - hf);
                    vh[c] = *(short*)&hb;
                    vl[c] = *(short*)&lb;
                }
                *(bfx8*)&val[0][grel][p][i * 8] = vh;
                *(bfx8*)&val[1][grel][p][i * 8] = vl;
            }
        }
        __syncthreads();
#pragma unroll
        for (int ks = 0; ks < 6; ++ks) {
            int grel = ks / 3;
            int ksl  = ks - grel * 3;
            int g    = 2 * r + grel;
            int kk   = ksl * 32 + ((lane >> 4) << 3);

            const u16* bp = wD + (size_t)(((g * 3 + ksl) * 4 + nf) * 2) * 512 + lane * 8;
            bfx8 bh = *(const bfx8*)bp;
            bfx8 bl = *(const bfx8*)(bp + 512);

            int row0 = lane & 15;
            bfx8 a0h = *(const bfx8*)&val[0][grel][row0][kk];
            bfx8 a0l = *(const bfx8*)&val[1][grel][row0][kk];
            bfx8 a1h = *(const bfx8*)&val[0][grel][row0 + 16][kk];
            bfx8 a1l = *(const bfx8*)&val[1][grel][row0 + 16][kk];

            acc[0] = __builtin_amdgcn_mfma_f32_16x16x32_bf16(a0h, bh, acc[0], 0, 0, 0);
            acc[0] = __builtin_amdgcn_mfma_f32_16x16x32_bf16(a0l, bh, acc[0], 0, 0, 0);
            acc[0] = __builtin_amdgcn_mfma_f32_16x16x32_bf16(a0h, bl, acc[0], 0, 0, 0);
            acc[1] = __builtin_amdgcn_mfma_f32_16x16x32_bf16(a1h, bh, acc[1], 0, 0, 0);
            acc[1] = __builtin_amdgcn_mfma_f32_16x16x32_bf16(a1l, bh, acc[1], 0, 0, 0);
            acc[1] = __builtin_amdgcn_mfma_f32_16x16x32_bf16(a1h, bl, acc[1], 0, 0, 0);
        }
    }

    __syncthreads();
    float* trans = (float*)&val[0][0][0][0];   // 64*36*4 = 9216 B
#pragma unroll
    for (int t = 0; t < 2; ++t) {
        int oc = nf * 16 + (lane & 15);
        int p4 = t * 16 + ((lane >> 4) << 2);
        *(fx4*)&trans[oc * 36 + p4] = acc[t];
    }
    __syncthreads();
#pragma unroll
    for (int t = 0; t < 2; ++t) {
        int f  = t * 256 + tid;           // 0..511
        int oc = f >> 3;                  // 0..63
        int c4 = f & 7;
        float4 v = *(float4*)&trans[oc * 36 + c4 * 4];
        float bb = bias[oc];
        v.x += bb; v.y += bb; v.z += bb; v.w += bb;
        *(float4*)&out[((size_t)b * O + oc) * HW + px0 + c4 * 4] = v;
    }
}

// ---------------- Launch ----------------
extern "C" void kernel_launch(void* const* d_in, const int* in_sizes, int n_in,
                              void* d_out, int out_size, void* d_ws, size_t ws_size,
                              hipStream_t stream) {
    (void)in_sizes; (void)n_in; (void)out_size; (void)ws_size;
    const float* x0         = (const float*)d_in[0];
    const float* x1         = (const float*)d_in[1];
    const float* pre_offset = (const float*)d_in[2];
    const float* pre_sim    = (const float*)d_in[3];
    const float* weight     = (const float*)d_in[4];
    const float* bias       = (const float*)d_in[5];
    const float* w_om       = (const float*)d_in[6];
    const float* b_om       = (const float*)d_in[7];
    float* out = (float*)d_out;

    // ws layout: rawoff | rawmsk | xbuf(x1p_hi,x1p_lo / x0T union) | wB2 | wD
    float* rawoff = (float*)d_ws;                       // B*OFF_C*HW floats
    float* rawmsk = rawoff + (size_t)B * OFF_C * HW;    // B*MSK_C*HW floats
    float* xbuf   = rawmsk + (size_t)B * MSK_C * HW;
    u16*   x1p_hi = (u16*)xbuf;                         // X1P_N u16
    u16*   x1p_lo = x1p_hi + (size_t)X1P_N;             // X1P_N u16
    float* x0T    = xbuf;                               // aliases x1p (after conv)
    u16*   wB2    = x1p_lo + (size_t)X1P_N;             // WB2_N u16
    u16*   wD     = wB2 + (size_t)WB2_N;                // WD_N u16

    {
        int total = WD_N + B * HW + B * PADP + WB2_N;   // 293896
        prep1_kernel<<<(total + 255) / 256, 256, 0, stream>>>(
            weight, w_om, x1, wD, x1p_hi, x1p_lo, wB2);
    }
    {
        conv_om_mfma_kernel<<<256, 1024, 0, stream>>>(
            x1p_hi, x1p_lo, wB2, b_om, rawoff, rawmsk);
    }
    {
        prep2_kernel<<<X0T_N / 256, 256, 0, stream>>>(x0, x0T);
    }
    {
        deform_mfma_kernel<<<1024, 256, 0, stream>>>(
            x0T, rawoff, rawmsk, pre_offset, pre_sim, wD, bias, out);
    }
}

// Round 23
// 80.558 us; speedup vs baseline: 1.3929x; 1.1933x over previous
//
#include <hip/hip_runtime.h>
#include <hip/hip_bf16.h>
#include <math.h>

// Problem constants
constexpr int B  = 2;
constexpr int C  = 64;
constexpr int H  = 128;
constexpr int W  = 128;
constexpr int O  = 64;
constexpr int DG = 8;
constexpr int K  = 3;
constexpr int KK = K * K;           // 9
constexpr int HW = H * W;           // 16384
constexpr int CG = C / DG;          // 8
constexpr int OM_C  = 3 * DG * KK;  // 216
constexpr int OFF_C = 2 * DG * KK;  // 144
constexpr int MSK_C = DG * KK;      // 72
constexpr float MRM = 10.0f;

typedef unsigned short u16;
typedef unsigned int   u32;
typedef short bfx8 __attribute__((ext_vector_type(8)));   // 8 bf16 (4 VGPRs)
typedef float fx4 __attribute__((ext_vector_type(4)));    // MFMA accumulator

// Sizes
constexpr int X0T_N  = B * C * HW;      // 2097152 u16 (x0 bf16 interleaved)
constexpr int WB2_STEP = 7168;          // u16 per (t,chunk) wh slab (14 KB)
constexpr int WB2_N  = 18 * WB2_STEP;   // 129024
constexpr int WD_N   = 8 * 3 * 4 * 2 * 512;  // 98304 u16 deform B-frags
constexpr int PW     = 130;             // padded width/height
constexpr int PADP   = PW * PW;         // 16900 padded pixels
constexpr int X1P_N  = B * PADP * C;    // u16 per buffer
constexpr int VKS    = 104;             // deform val k-stride

// tap deltas in padded-pixel u16 units
__device__ constexpr int TAPD[9] = {
    (-PW - 1) * 64, (-PW) * 64, (-PW + 1) * 64,
    (-1) * 64,      0,          (1) * 64,
    (PW - 1) * 64,  (PW) * 64,  (PW + 1) * 64
};

// fast transcendentals (single v_exp_f32 / v_rcp_f32; NaN-safe at +-inf)
__device__ __forceinline__ float fast_tanh(float x) {
    float e = __expf(2.0f * x);                       // inf for large x
    return 1.0f - 2.0f * __builtin_amdgcn_rcpf(e + 1.0f);
}
__device__ __forceinline__ float fast_sigmoid(float x) {
    return __builtin_amdgcn_rcpf(1.0f + __expf(-x));
}
__device__ __forceinline__ float bf2f(u16 v) {
    u32 u = ((u32)v) << 16;
    return __builtin_bit_cast(float, u);
}

// ---------------- prep1: wD (deform B-frags), padded x1 hi/lo, wB2 ---------
__global__ void __launch_bounds__(256)
prep1_kernel(const float* __restrict__ weight,
             const float* __restrict__ w_om,
             const float* __restrict__ x1,
             u16* __restrict__ wD,
             u16* __restrict__ x1p_hi,
             u16* __restrict__ x1p_lo,
             u16* __restrict__ wB2) {
    int idx = blockIdx.x * 256 + threadIdx.x;
    if (idx < WD_N) {
        int j    = idx & 7;
        int lane = (idx >> 3) & 63;
        int sel  = (idx >> 9) & 1;
        int nf   = (idx >> 10) & 3;
        int gks  = idx >> 12;           // 0..23
        int g = gks / 3, ks = gks - g * 3;
        int kg = ks * 32 + ((lane >> 4) << 3) + j;
        int oc = nf * 16 + (lane & 15);
        float v = 0.0f;
        if (kg < 72) {
            int i = kg >> 3, c = kg & 7;
            v = weight[oc * (C * KK) + (g * CG + c) * KK + i];
        }
        __hip_bfloat16 hb = __float2bfloat16(v);
        if (sel == 0) {
            wD[idx] = *(u16*)&hb;
        } else {
            float hf = __bfloat162float(hb);
            __hip_bfloat16 lb = __float2bfloat16(v - hf);
            wD[idx] = *(u16*)&lb;
        }
        return;
    }
    int i1 = idx - WD_N;
    if (i1 < B * HW) {   // transpose interior: x1 -> padded [p][ic] hi/lo
        int p = i1 & (HW - 1);
        int b = i1 >> 14;
        const float* xp = x1 + (size_t)b * C * HW + p;
        bfx8 vh[8], vl[8];
#pragma unroll
        for (int k = 0; k < 8; ++k) {
#pragma unroll
            for (int j = 0; j < 8; ++j) {
                float x = xp[(size_t)(k * 8 + j) * HW];
                __hip_bfloat16 hb = __float2bfloat16(x);
                float hf = __bfloat162float(hb);
                __hip_bfloat16 lb = __float2bfloat16(x - hf);
                vh[k][j] = *(short*)&hb;
                vl[k][j] = *(short*)&lb;
            }
        }
        int dpx = ((p >> 7) + 1) * PW + (p & (W - 1)) + 1;
        u16* dh = x1p_hi + ((size_t)b * PADP + dpx) * C;
        u16* dl = x1p_lo + ((size_t)b * PADP + dpx) * C;
#pragma unroll
        for (int k = 0; k < 8; ++k) {
            *(bfx8*)(dh + k * 8) = vh[k];
            *(bfx8*)(dl + k * 8) = vl[k];
        }
        return;
    }
    int i2 = i1 - B * HW;
    if (i2 < B * PADP) {  // zero the border pixels
        int b2 = i2 / PADP;
        int px = i2 - b2 * PADP;
        int rr = px / PW, cc = px - rr * PW;
        if (rr == 0 || rr == PW - 1 || cc == 0 || cc == PW - 1) {
            u16* zh = x1p_hi + ((size_t)b2 * PADP + px) * C;
            u16* zl = x1p_lo + ((size_t)b2 * PADP + px) * C;
            const bfx8 z = {0, 0, 0, 0, 0, 0, 0, 0};
#pragma unroll
            for (int k = 0; k < 8; ++k) {
                *(bfx8*)(zh + k * 8) = z;
                *(bfx8*)(zl + k * 8) = z;
            }
        }
        return;
    }
    int i3 = i2 - B * PADP;
    if (i3 < WB2_N) {
        // layout: [t 9][chunk 2][nfh 14][lane 64][j 8], wh only
        int step2 = i3 / WB2_STEP;
        int r     = i3 - step2 * WB2_STEP;
        int nfh  = r >> 9;
        int lane = (r >> 3) & 63;
        int j    = r & 7;
        int t = step2 >> 1, chunk = step2 & 1;
        int ic = chunk * 32 + ((lane >> 4) << 3) + j;
        int oc = (nfh << 4) + (lane & 15);
        float v = (oc < OM_C) ? w_om[oc * (C * KK) + ic * KK + t] : 0.0f;
        __hip_bfloat16 hb = __float2bfloat16(v);
        wB2[i3] = *(u16*)&hb;
    }
}

// ---------------- prep2: x0 channel-interleave to bf16 ----------------
__global__ void __launch_bounds__(256)
prep2_kernel(const float* __restrict__ x0, u16* __restrict__ x0Tb) {
    int idx = blockIdx.x * 256 + threadIdx.x;
    int p  = idx & (HW - 1);
    int ch = (idx >> 14) & (C - 1);
    int b  = idx >> 20;
    __hip_bfloat16 hb = __float2bfloat16(x0[idx]);
    x0Tb[((size_t)((b * DG + (ch >> 3)) * HW + p) << 3) + (ch & 7)] = *(u16*)&hb;
}

// ---------------- conv_offset_mask: raw-output epilogue (R22 verbatim) -----
__global__ void __launch_bounds__(1024, 4)
conv_om_mfma_kernel(const u16* __restrict__ x1p_hi,
                    const u16* __restrict__ x1p_lo,
                    const u16* __restrict__ wB2,
                    const float* __restrict__ b_om,
                    float* __restrict__ rawoff,
                    float* __restrict__ rawmsk) {
    __shared__ __align__(16) u16 smem[2][2 * WB2_STEP];   // 57,344 B

    int bid  = blockIdx.x;                        // 256 blocks
    int work = ((bid & 7) << 5) + (bid >> 3);     // XCD-chunked
    int b    = work >> 7;
    int px0  = (work & 127) << 7;                 // 128-px tile

    int tid  = threadIdx.x;
    int lane = tid & 63;
    int wid  = tid >> 6;             // 0..15
    int kidc = wid & 1;              // ic-chunk
    int wcol = (wid >> 1) & 1;
    int wrow = wid >> 2;             // 0..3

    fx4 acc[2][7];
#pragma unroll
    for (int mf = 0; mf < 2; ++mf)
#pragma unroll
        for (int nf = 0; nf < 7; ++nf) acc[mf][nf] = fx4{0.f, 0.f, 0.f, 0.f};

    int pA    = px0 + wrow * 32 + (lane & 15);
    int klane = (lane >> 4) << 3;
    int base0 = (((pA >> 7) + 1) * PW + (pA & (W - 1)) + 1) * C + kidc * 32 + klane;
    int base1 = base0 + 16 * C;

    const u16* xh_b = x1p_hi + (size_t)b * PADP * C;
    const u16* xl_b = x1p_lo + (size_t)b * PADP * C;

    // staging: 14 waves x 2 insts cover 28 x 1KB slots (both chunks, wh only)
    bool stager = (wid < 14);
    int  soff0 = (wid * 2 + 0) * 512 + lane * 8;
    int  soff1 = (wid * 2 + 1) * 512 + lane * 8;

    if (stager) {
        __builtin_amdgcn_global_load_lds(
            (const __attribute__((address_space(1))) u16*)(wB2 + soff0),
            (__attribute__((address_space(3))) u16*)(&smem[0][0] + soff0), 16, 0, 0);
        __builtin_amdgcn_global_load_lds(
            (const __attribute__((address_space(1))) u16*)(wB2 + soff1),
            (__attribute__((address_space(3))) u16*)(&smem[0][0] + soff1), 16, 0, 0);
    }
    bfx8 ahc0 = *(const bfx8*)(xh_b + base0 + TAPD[0]);
    bfx8 ahc1 = *(const bfx8*)(xh_b + base1 + TAPD[0]);
    bfx8 alc0 = *(const bfx8*)(xl_b + base0 + TAPD[0]);
    bfx8 alc1 = *(const bfx8*)(xl_b + base1 + TAPD[0]);
    __syncthreads();

#pragma unroll
    for (int t = 0; t < 9; ++t) {
        bfx8 ahn0, ahn1, aln0, aln1;
        if (t < 8) {
            if (stager) {
                const u16* src = wB2 + (size_t)(t + 1) * 2 * WB2_STEP;
                u16* dst = &smem[(t + 1) & 1][0];
                __builtin_amdgcn_global_load_lds(
                    (const __attribute__((address_space(1))) u16*)(src + soff0),
                    (__attribute__((address_space(3))) u16*)(dst + soff0), 16, 0, 0);
                __builtin_amdgcn_global_load_lds(
                    (const __attribute__((address_space(1))) u16*)(src + soff1),
                    (__attribute__((address_space(3))) u16*)(dst + soff1), 16, 0, 0);
            }
            int d = TAPD[t + 1];
            ahn0 = *(const bfx8*)(xh_b + base0 + d);
            ahn1 = *(const bfx8*)(xh_b + base1 + d);
            aln0 = *(const bfx8*)(xl_b + base0 + d);
            aln1 = *(const bfx8*)(xl_b + base1 + d);
        }
        const u16* slab = &smem[t & 1][kidc * WB2_STEP];
#pragma unroll
        for (int nf = 0; nf < 7; ++nf) {
            bfx8 bh = *(const bfx8*)(slab + ((wcol * 7 + nf) << 9) + (lane << 3));
            acc[0][nf] = __builtin_amdgcn_mfma_f32_16x16x32_bf16(ahc0, bh, acc[0][nf], 0, 0, 0);
            acc[0][nf] = __builtin_amdgcn_mfma_f32_16x16x32_bf16(alc0, bh, acc[0][nf], 0, 0, 0);
            acc[1][nf] = __builtin_amdgcn_mfma_f32_16x16x32_bf16(ahc1, bh, acc[1][nf], 0, 0, 0);
            acc[1][nf] = __builtin_amdgcn_mfma_f32_16x16x32_bf16(alc1, bh, acc[1][nf], 0, 0, 0);
        }
        __syncthreads();
        if (t < 8) {
            ahc0 = ahn0; ahc1 = ahn1; alc0 = aln0; alc1 = aln1;
        }
    }

    // kid reduction via LDS, 2 rounds over wcol; full 128-B line stores.
    fx4* red = (fx4*)&smem[0][0];
#pragma unroll
    for (int rc = 0; rc < 2; ++rc) {
        if (kidc == 1 && wcol == rc) {
#pragma unroll
            for (int mf = 0; mf < 2; ++mf)
#pragma unroll
                for (int nf = 0; nf < 7; ++nf)
                    red[(((wrow << 1) + mf) * 7 + nf) * 64 + lane] = acc[mf][nf];
        }
        __syncthreads();
        if (kidc == 0 && wcol == rc) {
#pragma unroll
            for (int nf = 0; nf < 7; ++nf) {
#pragma unroll
                for (int mf = 0; mf < 2; ++mf) {
                    fx4 v = acc[mf][nf] + red[(((wrow << 1) + mf) * 7 + nf) * 64 + lane];
                    int oc  = rc * 112 + nf * 16 + (lane & 15);
                    int pix = px0 + wrow * 32 + mf * 16 + ((lane >> 4) << 2);
                    if (oc < OM_C) {
                        float bb = b_om[oc];
                        float4 r;
                        r.x = v[0] + bb; r.y = v[1] + bb;
                        r.z = v[2] + bb; r.w = v[3] + bb;
                        if (oc < OFF_C) {
                            *(float4*)&rawoff[(size_t)(b * OFF_C + oc) * HW + pix] = r;
                        } else {
                            *(float4*)&rawmsk[(size_t)(b * MSK_C + oc - OFF_C) * HW + pix] = r;
                        }
                    }
                }
            }
        }
        __syncthreads();
    }
}

// ---------------- deform conv via MFMA, bf16 gathers ------------------
// R22 structure; x0 stored bf16 channel-interleaved -> ONE 16B load per
// bilinear corner (4 gathers/set instead of 8), halving L1 transactions.
__global__ void __launch_bounds__(256, 4)
deform_mfma_kernel(const u16* __restrict__ x0Tb,
                   const float* __restrict__ rawoff,
                   const float* __restrict__ rawmsk,
                   const float* __restrict__ pre_offset,
                   const float* __restrict__ pre_sim,
                   const u16* __restrict__ wD,
                   const float* __restrict__ bias,
                   float* __restrict__ out) {
    __shared__ __align__(16) u16 val[2][2][32][VKS];   // 26,624 B

    int bid  = blockIdx.x;                        // 1024 blocks
    int work = ((bid & 7) << 7) + (bid >> 3);     // XCD-chunked
    int b    = work >> 9;
    int px0  = (work & 511) << 5;

    int tid  = threadIdx.x;
    int lane = tid & 63;
    int nf   = tid >> 6;          // wave id = N-frag 0..3

    {
        const bfx8 z = {0, 0, 0, 0, 0, 0, 0, 0};
#pragma unroll
        for (int zz = 0; zz < 2; ++zz) {
            int zc = zz * 256 + tid;           // 0..511
            int sub  = zc & 3;
            int rest = zc >> 2;                // 0..127
            int p    = rest & 31;
            int grel = (rest >> 5) & 1;
            int hl   = rest >> 6;
            *(bfx8*)&val[hl][grel][p][72 + sub * 8] = z;
        }
    }

    fx4 acc[2];
    acc[0] = fx4{0.f, 0.f, 0.f, 0.f};
    acc[1] = fx4{0.f, 0.f, 0.f, 0.f};

    for (int r = 0; r < 4; ++r) {
        __syncthreads();
#pragma unroll
        for (int rep = 0; rep < 3; ++rep) {
            int s = rep * 256 + tid;
            if (s < 576) {
                int p    = s & 31;
                int rest = s >> 5;            // 0..17
                int grel = rest / 9;
                int i    = rest - grel * 9;
                int g    = 2 * r + grel;
                int gi   = g * 9 + i;
                int gp   = px0 + p;
                int h = gp >> 7, w = gp & (W - 1);

                size_t oyi = (size_t)(b * OFF_C + 2 * gi) * HW + gp;
                size_t oxi = (size_t)(b * OFF_C + 2 * gi + 1) * HW + gp;
                size_t mii = (size_t)(b * MSK_C + gi) * HW + gp;
                float offy = MRM * fast_tanh(rawoff[oyi]) + pre_offset[oyi];
                float offx = MRM * fast_tanh(rawoff[oxi]) + pre_offset[oxi];
                float m    = fast_sigmoid(rawmsk[mii] * pre_sim[mii]);

                float py = offy + (float)(h - 1 + i / 3);
                float px = offx + (float)(w - 1 + i % 3);
                float fy = floorf(py), fx = floorf(px);
                float ly = py - fy, lx = px - fx;
                float hy = 1.0f - ly, hx = 1.0f - lx;
                int y0 = (int)fy, x0i = (int)fx;
                int y1 = y0 + 1, x1i = x0i + 1;
                bool vy0 = (y0 >= 0) && (y0 < H);
                bool vy1 = (y1 >= 0) && (y1 < H);
                bool vx0 = (x0i >= 0) && (x0i < W);
                bool vx1 = (x1i >= 0) && (x1i < W);
                int cy0 = min(max(y0, 0), H - 1), cy1 = min(max(y1, 0), H - 1);
                int cx0 = min(max(x0i, 0), W - 1), cx1 = min(max(x1i, 0), W - 1);
                float w00 = hy * hx * ((vy0 && vx0) ? 1.0f : 0.0f) * m;
                float w01 = hy * lx * ((vy0 && vx1) ? 1.0f : 0.0f) * m;
                float w10 = ly * hx * ((vy1 && vx0) ? 1.0f : 0.0f) * m;
                float w11 = ly * lx * ((vy1 && vx1) ? 1.0f : 0.0f) * m;
                int i00 = cy0 * W + cx0, i01 = cy0 * W + cx1;
                int i10 = cy1 * W + cx0, i11 = cy1 * W + cx1;

                const u16* xg = x0Tb + (((size_t)(b * DG + g) * HW) << 3);
                bfx8 c00 = *(const bfx8*)(xg + ((size_t)i00 << 3));
                bfx8 c01 = *(const bfx8*)(xg + ((size_t)i01 << 3));
                bfx8 c10 = *(const bfx8*)(xg + ((size_t)i10 << 3));
                bfx8 c11 = *(const bfx8*)(xg + ((size_t)i11 << 3));

                float v[CG];
#pragma unroll
                for (int c = 0; c < CG; ++c) {
                    v[c] = w00 * bf2f((u16)c00[c]) + w01 * bf2f((u16)c01[c])
                         + w10 * bf2f((u16)c10[c]) + w11 * bf2f((u16)c11[c]);
                }

                bfx8 vh, vl;
#pragma unroll
                for (int c = 0; c < CG; ++c) {
                    __hip_bfloat16 hb = __float2bfloat16(v[c]);
                    float hf = __bfloat162float(hb);
                    __hip_bfloat16 lb = __float2bfloat16(v[c] - hf);
                    vh[c] = *(short*)&hb;
                    vl[c] = *(short*)&lb;
                }
                *(bfx8*)&val[0][grel][p][i * 8] = vh;
                *(bfx8*)&val[1][grel][p][i * 8] = vl;
            }
        }
        __syncthreads();
#pragma unroll
        for (int ks = 0; ks < 6; ++ks) {
            int grel = ks / 3;
            int ksl  = ks - grel * 3;
            int g    = 2 * r + grel;
            int kk   = ksl * 32 + ((lane >> 4) << 3);

            const u16* bp = wD + (size_t)(((g * 3 + ksl) * 4 + nf) * 2) * 512 + lane * 8;
            bfx8 bh = *(const bfx8*)bp;
            bfx8 bl = *(const bfx8*)(bp + 512);

            int row0 = lane & 15;
            bfx8 a0h = *(const bfx8*)&val[0][grel][row0][kk];
            bfx8 a0l = *(const bfx8*)&val[1][grel][row0][kk];
            bfx8 a1h = *(const bfx8*)&val[0][grel][row0 + 16][kk];
            bfx8 a1l = *(const bfx8*)&val[1][grel][row0 + 16][kk];

            acc[0] = __builtin_amdgcn_mfma_f32_16x16x32_bf16(a0h, bh, acc[0], 0, 0, 0);
            acc[0] = __builtin_amdgcn_mfma_f32_16x16x32_bf16(a0l, bh, acc[0], 0, 0, 0);
            acc[0] = __builtin_amdgcn_mfma_f32_16x16x32_bf16(a0h, bl, acc[0], 0, 0, 0);
            acc[1] = __builtin_amdgcn_mfma_f32_16x16x32_bf16(a1h, bh, acc[1], 0, 0, 0);
            acc[1] = __builtin_amdgcn_mfma_f32_16x16x32_bf16(a1l, bh, acc[1], 0, 0, 0);
            acc[1] = __builtin_amdgcn_mfma_f32_16x16x32_bf16(a1h, bl, acc[1], 0, 0, 0);
        }
    }

    __syncthreads();
    float* trans = (float*)&val[0][0][0][0];   // 64*36*4 = 9216 B
#pragma unroll
    for (int t = 0; t < 2; ++t) {
        int oc = nf * 16 + (lane & 15);
        int p4 = t * 16 + ((lane >> 4) << 2);
        *(fx4*)&trans[oc * 36 + p4] = acc[t];
    }
    __syncthreads();
#pragma unroll
    for (int t = 0; t < 2; ++t) {
        int f  = t * 256 + tid;           // 0..511
        int oc = f >> 3;                  // 0..63
        int c4 = f & 7;
        float4 v = *(float4*)&trans[oc * 36 + c4 * 4];
        float bb = bias[oc];
        v.x += bb; v.y += bb; v.z += bb; v.w += bb;
        *(float4*)&out[((size_t)b * O + oc) * HW + px0 + c4 * 4] = v;
    }
}

// ---------------- Launch ----------------
extern "C" void kernel_launch(void* const* d_in, const int* in_sizes, int n_in,
                              void* d_out, int out_size, void* d_ws, size_t ws_size,
                              hipStream_t stream) {
    (void)in_sizes; (void)n_in; (void)out_size; (void)ws_size;
    const float* x0         = (const float*)d_in[0];
    const float* x1         = (const float*)d_in[1];
    const float* pre_offset = (const float*)d_in[2];
    const float* pre_sim    = (const float*)d_in[3];
    const float* weight     = (const float*)d_in[4];
    const float* bias       = (const float*)d_in[5];
    const float* w_om       = (const float*)d_in[6];
    const float* b_om       = (const float*)d_in[7];
    float* out = (float*)d_out;

    // ws layout: rawoff | rawmsk | xbuf(x1p_hi,x1p_lo / x0Tb union) | wB2 | wD
    float* rawoff = (float*)d_ws;                       // B*OFF_C*HW floats
    float* rawmsk = rawoff + (size_t)B * OFF_C * HW;    // B*MSK_C*HW floats
    float* xbuf   = rawmsk + (size_t)B * MSK_C * HW;
    u16*   x1p_hi = (u16*)xbuf;                         // X1P_N u16
    u16*   x1p_lo = x1p_hi + (size_t)X1P_N;             // X1P_N u16
    u16*   x0Tb   = (u16*)xbuf;                         // aliases x1p (after conv)
    u16*   wB2    = x1p_lo + (size_t)X1P_N;             // WB2_N u16
    u16*   wD     = wB2 + (size_t)WB2_N;                // WD_N u16

    {
        int total = WD_N + B * HW + B * PADP + WB2_N;   // 293896
        prep1_kernel<<<(total + 255) / 256, 256, 0, stream>>>(
            weight, w_om, x1, wD, x1p_hi, x1p_lo, wB2);
    }
    {
        conv_om_mfma_kernel<<<256, 1024, 0, stream>>>(
            x1p_hi, x1p_lo, wB2, b_om, rawoff, rawmsk);
    }
    {
        prep2_kernel<<<X0T_N / 256, 256, 0, stream>>>(x0, x0Tb);
    }
    {
        deform_mfma_kernel<<<1024, 256, 0, stream>>>(
            x0Tb, rawoff, rawmsk, pre_offset, pre_sim, wD, bias, out);
    }
}

// Round 24
// 79.020 us; speedup vs baseline: 1.4200x; 1.0195x over previous
//
#include <hip/hip_runtime.h>
#include <hip/hip_bf16.h>
#include <math.h>

// Problem constants
constexpr int B  = 2;
constexpr int C  = 64;
constexpr int H  = 128;
constexpr int W  = 128;
constexpr int O  = 64;
constexpr int DG = 8;
constexpr int K  = 3;
constexpr int KK = K * K;           // 9
constexpr int HW = H * W;           // 16384
constexpr int CG = C / DG;          // 8
constexpr int OM_C  = 3 * DG * KK;  // 216
constexpr int OFF_C = 2 * DG * KK;  // 144
constexpr int MSK_C = DG * KK;      // 72
constexpr float MRM = 10.0f;

typedef unsigned short u16;
typedef unsigned int   u32;
typedef short bfx8 __attribute__((ext_vector_type(8)));   // 8 bf16 (4 VGPRs)
typedef short bfx4 __attribute__((ext_vector_type(4)));   // 4 bf16 (2 VGPRs)
typedef float fx4 __attribute__((ext_vector_type(4)));    // MFMA accumulator

// Sizes
constexpr int X0T_N  = B * C * HW;      // 2097152 u16 (x0 bf16 interleaved)
constexpr int WB2_STEP = 7168;          // u16 per (t,chunk) wh slab (14 KB)
constexpr int WB2_N  = 18 * WB2_STEP;   // 129024
constexpr int WD_N   = 8 * 3 * 4 * 2 * 512;  // 98304 u16 deform B-frags
constexpr int PW     = 130;             // padded width/height
constexpr int PADP   = PW * PW;         // 16900 padded pixels
constexpr int X1P_N  = B * PADP * C;    // u16 per buffer
constexpr int VKS    = 104;             // deform val k-stride

// tap deltas in padded-pixel u16 units
__device__ constexpr int TAPD[9] = {
    (-PW - 1) * 64, (-PW) * 64, (-PW + 1) * 64,
    (-1) * 64,      0,          (1) * 64,
    (PW - 1) * 64,  (PW) * 64,  (PW + 1) * 64
};

// fast transcendentals (single v_exp_f32 / v_rcp_f32; NaN-safe at +-inf)
__device__ __forceinline__ float fast_tanh(float x) {
    float e = __expf(2.0f * x);                       // inf for large x
    return 1.0f - 2.0f * __builtin_amdgcn_rcpf(e + 1.0f);
}
__device__ __forceinline__ float fast_sigmoid(float x) {
    return __builtin_amdgcn_rcpf(1.0f + __expf(-x));
}
__device__ __forceinline__ float bf2f(u16 v) {
    u32 u = ((u32)v) << 16;
    return __builtin_bit_cast(float, u);
}

// ---------------- prep1: wD (deform B-frags), padded x1 hi/lo, wB2 ---------
__global__ void __launch_bounds__(256)
prep1_kernel(const float* __restrict__ weight,
             const float* __restrict__ w_om,
             const float* __restrict__ x1,
             u16* __restrict__ wD,
             u16* __restrict__ x1p_hi,
             u16* __restrict__ x1p_lo,
             u16* __restrict__ wB2) {
    int idx = blockIdx.x * 256 + threadIdx.x;
    if (idx < WD_N) {
        int j    = idx & 7;
        int lane = (idx >> 3) & 63;
        int sel  = (idx >> 9) & 1;
        int nf   = (idx >> 10) & 3;
        int gks  = idx >> 12;           // 0..23
        int g = gks / 3, ks = gks - g * 3;
        int kg = ks * 32 + ((lane >> 4) << 3) + j;
        int oc = nf * 16 + (lane & 15);
        float v = 0.0f;
        if (kg < 72) {
            int i = kg >> 3, c = kg & 7;
            v = weight[oc * (C * KK) + (g * CG + c) * KK + i];
        }
        __hip_bfloat16 hb = __float2bfloat16(v);
        if (sel == 0) {
            wD[idx] = *(u16*)&hb;
        } else {
            float hf = __bfloat162float(hb);
            __hip_bfloat16 lb = __float2bfloat16(v - hf);
            wD[idx] = *(u16*)&lb;
        }
        return;
    }
    int i1 = idx - WD_N;
    if (i1 < B * HW) {   // transpose interior: x1 -> padded [p][ic] hi/lo
        int p = i1 & (HW - 1);
        int b = i1 >> 14;
        const float* xp = x1 + (size_t)b * C * HW + p;
        bfx8 vh[8], vl[8];
#pragma unroll
        for (int k = 0; k < 8; ++k) {
#pragma unroll
            for (int j = 0; j < 8; ++j) {
                float x = xp[(size_t)(k * 8 + j) * HW];
                __hip_bfloat16 hb = __float2bfloat16(x);
                float hf = __bfloat162float(hb);
                __hip_bfloat16 lb = __float2bfloat16(x - hf);
                vh[k][j] = *(short*)&hb;
                vl[k][j] = *(short*)&lb;
            }
        }
        int dpx = ((p >> 7) + 1) * PW + (p & (W - 1)) + 1;
        u16* dh = x1p_hi + ((size_t)b * PADP + dpx) * C;
        u16* dl = x1p_lo + ((size_t)b * PADP + dpx) * C;
#pragma unroll
        for (int k = 0; k < 8; ++k) {
            *(bfx8*)(dh + k * 8) = vh[k];
            *(bfx8*)(dl + k * 8) = vl[k];
        }
        return;
    }
    int i2 = i1 - B * HW;
    if (i2 < B * PADP) {  // zero the border pixels
        int b2 = i2 / PADP;
        int px = i2 - b2 * PADP;
        int rr = px / PW, cc = px - rr * PW;
        if (rr == 0 || rr == PW - 1 || cc == 0 || cc == PW - 1) {
            u16* zh = x1p_hi + ((size_t)b2 * PADP + px) * C;
            u16* zl = x1p_lo + ((size_t)b2 * PADP + px) * C;
            const bfx8 z = {0, 0, 0, 0, 0, 0, 0, 0};
#pragma unroll
            for (int k = 0; k < 8; ++k) {
                *(bfx8*)(zh + k * 8) = z;
                *(bfx8*)(zl + k * 8) = z;
            }
        }
        return;
    }
    int i3 = i2 - B * PADP;
    if (i3 < WB2_N) {
        // layout: [t 9][chunk 2][nfh 14][lane 64][j 8], wh only
        int step2 = i3 / WB2_STEP;
        int r     = i3 - step2 * WB2_STEP;
        int nfh  = r >> 9;
        int lane = (r >> 3) & 63;
        int j    = r & 7;
        int t = step2 >> 1, chunk = step2 & 1;
        int ic = chunk * 32 + ((lane >> 4) << 3) + j;
        int oc = (nfh << 4) + (lane & 15);
        float v = (oc < OM_C) ? w_om[oc * (C * KK) + ic * KK + t] : 0.0f;
        __hip_bfloat16 hb = __float2bfloat16(v);
        wB2[i3] = *(u16*)&hb;
    }
}

// ---------------- prep2: x0 -> bf16 channel-interleaved, coalesced --------
// One thread per (b, g, p): 8 coalesced plane reads, one contiguous 16-B
// write. (Old version wrote 2-B elements at 16-B stride with each 128-B
// line split across 8 blocks -> ~8x write amplification.)
__global__ void __launch_bounds__(256)
prep2_kernel(const float* __restrict__ x0, u16* __restrict__ x0Tb) {
    int idx = blockIdx.x * 256 + threadIdx.x;   // B*DG*HW = 262144
    int p = idx & (HW - 1);
    int g = (idx >> 14) & (DG - 1);
    int b = idx >> 17;
    const float* src = x0 + ((size_t)(b * C + g * CG) * HW) + p;
    bfx8 v;
#pragma unroll
    for (int c = 0; c < CG; ++c) {
        __hip_bfloat16 hb = __float2bfloat16(src[(size_t)c * HW]);
        v[c] = *(short*)&hb;
    }
    *(bfx8*)(x0Tb + (((size_t)(b * DG + g) * HW + p) << 3)) = v;
}

// ---------------- conv_offset_mask: raw-output epilogue -------------------
// R23 verbatim except rawmsk is stored as bf16 (mask-path rounding is
// second-order: delta_m ~ 1e-4 -> output ~7e-5).
__global__ void __launch_bounds__(1024, 4)
conv_om_mfma_kernel(const u16* __restrict__ x1p_hi,
                    const u16* __restrict__ x1p_lo,
                    const u16* __restrict__ wB2,
                    const float* __restrict__ b_om,
                    float* __restrict__ rawoff,
                    u16* __restrict__ rawmsk16) {
    __shared__ __align__(16) u16 smem[2][2 * WB2_STEP];   // 57,344 B

    int bid  = blockIdx.x;                        // 256 blocks
    int work = ((bid & 7) << 5) + (bid >> 3);     // XCD-chunked
    int b    = work >> 7;
    int px0  = (work & 127) << 7;                 // 128-px tile

    int tid  = threadIdx.x;
    int lane = tid & 63;
    int wid  = tid >> 6;             // 0..15
    int kidc = wid & 1;              // ic-chunk
    int wcol = (wid >> 1) & 1;
    int wrow = wid >> 2;             // 0..3

    fx4 acc[2][7];
#pragma unroll
    for (int mf = 0; mf < 2; ++mf)
#pragma unroll
        for (int nf = 0; nf < 7; ++nf) acc[mf][nf] = fx4{0.f, 0.f, 0.f, 0.f};

    int pA    = px0 + wrow * 32 + (lane & 15);
    int klane = (lane >> 4) << 3;
    int base0 = (((pA >> 7) + 1) * PW + (pA & (W - 1)) + 1) * C + kidc * 32 + klane;
    int base1 = base0 + 16 * C;

    const u16* xh_b = x1p_hi + (size_t)b * PADP * C;
    const u16* xl_b = x1p_lo + (size_t)b * PADP * C;

    // staging: 14 waves x 2 insts cover 28 x 1KB slots (both chunks, wh only)
    bool stager = (wid < 14);
    int  soff0 = (wid * 2 + 0) * 512 + lane * 8;
    int  soff1 = (wid * 2 + 1) * 512 + lane * 8;

    if (stager) {
        __builtin_amdgcn_global_load_lds(
            (const __attribute__((address_space(1))) u16*)(wB2 + soff0),
            (__attribute__((address_space(3))) u16*)(&smem[0][0] + soff0), 16, 0, 0);
        __builtin_amdgcn_global_load_lds(
            (const __attribute__((address_space(1))) u16*)(wB2 + soff1),
            (__attribute__((address_space(3))) u16*)(&smem[0][0] + soff1), 16, 0, 0);
    }
    bfx8 ahc0 = *(const bfx8*)(xh_b + base0 + TAPD[0]);
    bfx8 ahc1 = *(const bfx8*)(xh_b + base1 + TAPD[0]);
    bfx8 alc0 = *(const bfx8*)(xl_b + base0 + TAPD[0]);
    bfx8 alc1 = *(const bfx8*)(xl_b + base1 + TAPD[0]);
    __syncthreads();

#pragma unroll
    for (int t = 0; t < 9; ++t) {
        bfx8 ahn0, ahn1, aln0, aln1;
        if (t < 8) {
            if (stager) {
                const u16* src = wB2 + (size_t)(t + 1) * 2 * WB2_STEP;
                u16* dst = &smem[(t + 1) & 1][0];
                __builtin_amdgcn_global_load_lds(
                    (const __attribute__((address_space(1))) u16*)(src + soff0),
                    (__attribute__((address_space(3))) u16*)(dst + soff0), 16, 0, 0);
                __builtin_amdgcn_global_load_lds(
                    (const __attribute__((address_space(1))) u16*)(src + soff1),
                    (__attribute__((address_space(3))) u16*)(dst + soff1), 16, 0, 0);
            }
            int d = TAPD[t + 1];
            ahn0 = *(const bfx8*)(xh_b + base0 + d);
            ahn1 = *(const bfx8*)(xh_b + base1 + d);
            aln0 = *(const bfx8*)(xl_b + base0 + d);
            aln1 = *(const bfx8*)(xl_b + base1 + d);
        }
        const u16* slab = &smem[t & 1][kidc * WB2_STEP];
#pragma unroll
        for (int nf = 0; nf < 7; ++nf) {
            bfx8 bh = *(const bfx8*)(slab + ((wcol * 7 + nf) << 9) + (lane << 3));
            acc[0][nf] = __builtin_amdgcn_mfma_f32_16x16x32_bf16(ahc0, bh, acc[0][nf], 0, 0, 0);
            acc[0][nf] = __builtin_amdgcn_mfma_f32_16x16x32_bf16(alc0, bh, acc[0][nf], 0, 0, 0);
            acc[1][nf] = __builtin_amdgcn_mfma_f32_16x16x32_bf16(ahc1, bh, acc[1][nf], 0, 0, 0);
            acc[1][nf] = __builtin_amdgcn_mfma_f32_16x16x32_bf16(alc1, bh, acc[1][nf], 0, 0, 0);
        }
        __syncthreads();
        if (t < 8) {
            ahc0 = ahn0; ahc1 = ahn1; alc0 = aln0; alc1 = aln1;
        }
    }

    // kid reduction via LDS, 2 rounds over wcol; full-line stores.
    fx4* red = (fx4*)&smem[0][0];
#pragma unroll
    for (int rc = 0; rc < 2; ++rc) {
        if (kidc == 1 && wcol == rc) {
#pragma unroll
            for (int mf = 0; mf < 2; ++mf)
#pragma unroll
                for (int nf = 0; nf < 7; ++nf)
                    red[(((wrow << 1) + mf) * 7 + nf) * 64 + lane] = acc[mf][nf];
        }
        __syncthreads();
        if (kidc == 0 && wcol == rc) {
#pragma unroll
            for (int nf = 0; nf < 7; ++nf) {
#pragma unroll
                for (int mf = 0; mf < 2; ++mf) {
                    fx4 v = acc[mf][nf] + red[(((wrow << 1) + mf) * 7 + nf) * 64 + lane];
                    int oc  = rc * 112 + nf * 16 + (lane & 15);
                    int pix = px0 + wrow * 32 + mf * 16 + ((lane >> 4) << 2);
                    if (oc < OM_C) {
                        float bb = b_om[oc];
                        if (oc < OFF_C) {
                            float4 r;
                            r.x = v[0] + bb; r.y = v[1] + bb;
                            r.z = v[2] + bb; r.w = v[3] + bb;
                            *(float4*)&rawoff[(size_t)(b * OFF_C + oc) * HW + pix] = r;
                        } else {
                            bfx4 rm;
#pragma unroll
                            for (int q = 0; q < 4; ++q) {
                                __hip_bfloat16 hb = __float2bfloat16(v[q] + bb);
                                rm[q] = *(short*)&hb;
                            }
                            *(bfx4*)&rawmsk16[(size_t)(b * MSK_C + oc - OFF_C) * HW + pix] = rm;
                        }
                    }
                }
            }
        }
        __syncthreads();
    }
}

// ---------------- deform conv via MFMA, bf16 gathers (R23 + bf16 rawmsk) ---
__global__ void __launch_bounds__(256, 4)
deform_mfma_kernel(const u16* __restrict__ x0Tb,
                   const float* __restrict__ rawoff,
                   const u16* __restrict__ rawmsk16,
                   const float* __restrict__ pre_offset,
                   const float* __restrict__ pre_sim,
                   const u16* __restrict__ wD,
                   const float* __restrict__ bias,
                   float* __restrict__ out) {
    __shared__ __align__(16) u16 val[2][2][32][VKS];   // 26,624 B

    int bid  = blockIdx.x;                        // 1024 blocks
    int work = ((bid & 7) << 7) + (bid >> 3);     // XCD-chunked
    int b    = work >> 9;
    int px0  = (work & 511) << 5;

    int tid  = threadIdx.x;
    int lane = tid & 63;
    int nf   = tid >> 6;          // wave id = N-frag 0..3

    {
        const bfx8 z = {0, 0, 0, 0, 0, 0, 0, 0};
#pragma unroll
        for (int zz = 0; zz < 2; ++zz) {
            int zc = zz * 256 + tid;           // 0..511
            int sub  = zc & 3;
            int rest = zc >> 2;                // 0..127
            int p    = rest & 31;
            int grel = (rest >> 5) & 1;
            int hl   = rest >> 6;
            *(bfx8*)&val[hl][grel][p][72 + sub * 8] = z;
        }
    }

    fx4 acc[2];
    acc[0] = fx4{0.f, 0.f, 0.f, 0.f};
    acc[1] = fx4{0.f, 0.f, 0.f, 0.f};

    for (int r = 0; r < 4; ++r) {
        __syncthreads();
#pragma unroll
        for (int rep = 0; rep < 3; ++rep) {
            int s = rep * 256 + tid;
            if (s < 576) {
                int p    = s & 31;
                int rest = s >> 5;            // 0..17
                int grel = rest / 9;
                int i    = rest - grel * 9;
                int g    = 2 * r + grel;
                int gi   = g * 9 + i;
                int gp   = px0 + p;
                int h = gp >> 7, w = gp & (W - 1);

                size_t oyi = (size_t)(b * OFF_C + 2 * gi) * HW + gp;
                size_t oxi = (size_t)(b * OFF_C + 2 * gi + 1) * HW + gp;
                size_t mii = (size_t)(b * MSK_C + gi) * HW + gp;
                float offy = MRM * fast_tanh(rawoff[oyi]) + pre_offset[oyi];
                float offx = MRM * fast_tanh(rawoff[oxi]) + pre_offset[oxi];
                float m    = fast_sigmoid(bf2f(rawmsk16[mii]) * pre_sim[mii]);

                float py = offy + (float)(h - 1 + i / 3);
                float px = offx + (float)(w - 1 + i % 3);
                float fy = floorf(py), fx = floorf(px);
                float ly = py - fy, lx = px - fx;
                float hy = 1.0f - ly, hx = 1.0f - lx;
                int y0 = (int)fy, x0i = (int)fx;
                int y1 = y0 + 1, x1i = x0i + 1;
                bool vy0 = (y0 >= 0) && (y0 < H);
                bool vy1 = (y1 >= 0) && (y1 < H);
                bool vx0 = (x0i >= 0) && (x0i < W);
                bool vx1 = (x1i >= 0) && (x1i < W);
                int cy0 = min(max(y0, 0), H - 1), cy1 = min(max(y1, 0), H - 1);
                int cx0 = min(max(x0i, 0), W - 1), cx1 = min(max(x1i, 0), W - 1);
                float w00 = hy * hx * ((vy0 && vx0) ? 1.0f : 0.0f) * m;
                float w01 = hy * lx * ((vy0 && vx1) ? 1.0f : 0.0f) * m;
                float w10 = ly * hx * ((vy1 && vx0) ? 1.0f : 0.0f) * m;
                float w11 = ly * lx * ((vy1 && vx1) ? 1.0f : 0.0f) * m;
                int i00 = cy0 * W + cx0, i01 = cy0 * W + cx1;
                int i10 = cy1 * W + cx0, i11 = cy1 * W + cx1;

                const u16* xg = x0Tb + (((size_t)(b * DG + g) * HW) << 3);
                bfx8 c00 = *(const bfx8*)(xg + ((size_t)i00 << 3));
                bfx8 c01 = *(const bfx8*)(xg + ((size_t)i01 << 3));
                bfx8 c10 = *(const bfx8*)(xg + ((size_t)i10 << 3));
                bfx8 c11 = *(const bfx8*)(xg + ((size_t)i11 << 3));

                float v[CG];
#pragma unroll
                for (int c = 0; c < CG; ++c) {
                    v[c] = w00 * bf2f((u16)c00[c]) + w01 * bf2f((u16)c01[c])
                         + w10 * bf2f((u16)c10[c]) + w11 * bf2f((u16)c11[c]);
                }

                bfx8 vh, vl;
#pragma unroll
                for (int c = 0; c < CG; ++c) {
                    __hip_bfloat16 hb = __float2bfloat16(v[c]);
                    float hf = __bfloat162float(hb);
                    __hip_bfloat16 lb = __float2bfloat16(v[c] - hf);
                    vh[c] = *(short*)&hb;
                    vl[c] = *(short*)&lb;
                }
                *(bfx8*)&val[0][grel][p][i * 8] = vh;
                *(bfx8*)&val[1][grel][p][i * 8] = vl;
            }
        }
        __syncthreads();
#pragma unroll
        for (int ks = 0; ks < 6; ++ks) {
            int grel = ks / 3;
            int ksl  = ks - grel * 3;
            int g    = 2 * r + grel;
            int kk   = ksl * 32 + ((lane >> 4) << 3);

            const u16* bp = wD + (size_t)(((g * 3 + ksl) * 4 + nf) * 2) * 512 + lane * 8;
            bfx8 bh = *(const bfx8*)bp;
            bfx8 bl = *(const bfx8*)(bp + 512);

            int row0 = lane & 15;
            bfx8 a0h = *(const bfx8*)&val[0][grel][row0][kk];
            bfx8 a0l = *(const bfx8*)&val[1][grel][row0][kk];
            bfx8 a1h = *(const bfx8*)&val[0][grel][row0 + 16][kk];
            bfx8 a1l = *(const bfx8*)&val[1][grel][row0 + 16][kk];

            acc[0] = __builtin_amdgcn_mfma_f32_16x16x32_bf16(a0h, bh, acc[0], 0, 0, 0);
            acc[0] = __builtin_amdgcn_mfma_f32_16x16x32_bf16(a0l, bh, acc[0], 0, 0, 0);
            acc[0] = __builtin_amdgcn_mfma_f32_16x16x32_bf16(a0h, bl, acc[0], 0, 0, 0);
            acc[1] = __builtin_amdgcn_mfma_f32_16x16x32_bf16(a1h, bh, acc[1], 0, 0, 0);
            acc[1] = __builtin_amdgcn_mfma_f32_16x16x32_bf16(a1l, bh, acc[1], 0, 0, 0);
            acc[1] = __builtin_amdgcn_mfma_f32_16x16x32_bf16(a1h, bl, acc[1], 0, 0, 0);
        }
    }

    __syncthreads();
    float* trans = (float*)&val[0][0][0][0];   // 64*36*4 = 9216 B
#pragma unroll
    for (int t = 0; t < 2; ++t) {
        int oc = nf * 16 + (lane & 15);
        int p4 = t * 16 + ((lane >> 4) << 2);
        *(fx4*)&trans[oc * 36 + p4] = acc[t];
    }
    __syncthreads();
#pragma unroll
    for (int t = 0; t < 2; ++t) {
        int f  = t * 256 + tid;           // 0..511
        int oc = f >> 3;                  // 0..63
        int c4 = f & 7;
        float4 v = *(float4*)&trans[oc * 36 + c4 * 4];
        float bb = bias[oc];
        v.x += bb; v.y += bb; v.z += bb; v.w += bb;
        *(float4*)&out[((size_t)b * O + oc) * HW + px0 + c4 * 4] = v;
    }
}

// ---------------- Launch ----------------
extern "C" void kernel_launch(void* const* d_in, const int* in_sizes, int n_in,
                              void* d_out, int out_size, void* d_ws, size_t ws_size,
                              hipStream_t stream) {
    (void)in_sizes; (void)n_in; (void)out_size; (void)ws_size;
    const float* x0         = (const float*)d_in[0];
    const float* x1         = (const float*)d_in[1];
    const float* pre_offset = (const float*)d_in[2];
    const float* pre_sim    = (const float*)d_in[3];
    const float* weight     = (const float*)d_in[4];
    const float* bias       = (const float*)d_in[5];
    const float* w_om       = (const float*)d_in[6];
    const float* b_om       = (const float*)d_in[7];
    float* out = (float*)d_out;

    // ws layout: rawoff(f32) | rawmsk(bf16) | xbuf(x1p_hi,x1p_lo / x0Tb) | wB2 | wD
    float* rawoff   = (float*)d_ws;                       // B*OFF_C*HW floats
    u16*   rawmsk16 = (u16*)(rawoff + (size_t)B * OFF_C * HW);  // B*MSK_C*HW u16
    u16*   xbuf     = rawmsk16 + (size_t)B * MSK_C * HW;
    u16*   x1p_hi = xbuf;                               // X1P_N u16
    u16*   x1p_lo = x1p_hi + (size_t)X1P_N;             // X1P_N u16
    u16*   x0Tb   = xbuf;                               // aliases x1p (after conv)
    u16*   wB2    = x1p_lo + (size_t)X1P_N;             // WB2_N u16
    u16*   wD     = wB2 + (size_t)WB2_N;                // WD_N u16

    {
        int total = WD_N + B * HW + B * PADP + WB2_N;   // 293896
        prep1_kernel<<<(total + 255) / 256, 256, 0, stream>>>(
            weight, w_om, x1, wD, x1p_hi, x1p_lo, wB2);
    }
    {
        conv_om_mfma_kernel<<<256, 1024, 0, stream>>>(
            x1p_hi, x1p_lo, wB2, b_om, rawoff, rawmsk16);
    }
    {
        prep2_kernel<<<(B * DG * HW) / 256, 256, 0, stream>>>(x0, x0Tb);
    }
    {
        deform_mfma_kernel<<<1024, 256, 0, stream>>>(
            x0Tb, rawoff, rawmsk16, pre_offset, pre_sim, wD, bias, out);
    }
}

// Round 25
// 72.464 us; speedup vs baseline: 1.5484x; 1.0905x over previous
//
#include <hip/hip_runtime.h>
#include <hip/hip_bf16.h>
#include <math.h>

// Problem constants
constexpr int B  = 2;
constexpr int C  = 64;
constexpr int H  = 128;
constexpr int W  = 128;
constexpr int O  = 64;
constexpr int DG = 8;
constexpr int K  = 3;
constexpr int KK = K * K;           // 9
constexpr int HW = H * W;           // 16384
constexpr int CG = C / DG;          // 8
constexpr int OM_C  = 3 * DG * KK;  // 216
constexpr int OFF_C = 2 * DG * KK;  // 144
constexpr int MSK_C = DG * KK;      // 72
constexpr float MRM = 10.0f;

typedef unsigned short u16;
typedef unsigned int   u32;
typedef short bfx8 __attribute__((ext_vector_type(8)));   // 8 bf16 (4 VGPRs)
typedef short bfx4 __attribute__((ext_vector_type(4)));   // 4 bf16 (2 VGPRs)
typedef float fx4 __attribute__((ext_vector_type(4)));    // MFMA accumulator

// Sizes
constexpr int X0T_N  = B * C * HW;      // 2097152 u16 (x0 bf16 interleaved)
constexpr int WB2_STEP = 7168;          // u16 per (t,chunk) wh slab (14 KB)
constexpr int WB2_N  = 18 * WB2_STEP;   // 129024
constexpr int WD_N   = 8 * 3 * 4 * 2 * 512;  // 98304 u16 deform B-frags
constexpr int PW     = 130;             // padded width/height
constexpr int PADP   = PW * PW;         // 16900 padded pixels
constexpr int X1P_N  = B * PADP * C;    // u16 per buffer
constexpr int VKS    = 104;             // deform val k-stride

// tap deltas in padded-pixel u16 units
__device__ constexpr int TAPD[9] = {
    (-PW - 1) * 64, (-PW) * 64, (-PW + 1) * 64,
    (-1) * 64,      0,          (1) * 64,
    (PW - 1) * 64,  (PW) * 64,  (PW + 1) * 64
};

// fast transcendentals (single v_exp_f32 / v_rcp_f32; NaN-safe at +-inf)
__device__ __forceinline__ float fast_tanh(float x) {
    float e = __expf(2.0f * x);                       // inf for large x
    return 1.0f - 2.0f * __builtin_amdgcn_rcpf(e + 1.0f);
}
__device__ __forceinline__ float fast_sigmoid(float x) {
    return __builtin_amdgcn_rcpf(1.0f + __expf(-x));
}
__device__ __forceinline__ float bf2f(u16 v) {
    u32 u = ((u32)v) << 16;
    return __builtin_bit_cast(float, u);
}

// ---------------- prep1: wD (deform B-frags), padded x1 hi/lo, wB2 ---------
__global__ void __launch_bounds__(256)
prep1_kernel(const float* __restrict__ weight,
             const float* __restrict__ w_om,
             const float* __restrict__ x1,
             u16* __restrict__ wD,
             u16* __restrict__ x1p_hi,
             u16* __restrict__ x1p_lo,
             u16* __restrict__ wB2) {
    int idx = blockIdx.x * 256 + threadIdx.x;
    if (idx < WD_N) {
        int j    = idx & 7;
        int lane = (idx >> 3) & 63;
        int sel  = (idx >> 9) & 1;
        int nf   = (idx >> 10) & 3;
        int gks  = idx >> 12;           // 0..23
        int g = gks / 3, ks = gks - g * 3;
        int kg = ks * 32 + ((lane >> 4) << 3) + j;
        int oc = nf * 16 + (lane & 15);
        float v = 0.0f;
        if (kg < 72) {
            int i = kg >> 3, c = kg & 7;
            v = weight[oc * (C * KK) + (g * CG + c) * KK + i];
        }
        __hip_bfloat16 hb = __float2bfloat16(v);
        if (sel == 0) {
            wD[idx] = *(u16*)&hb;
        } else {
            float hf = __bfloat162float(hb);
            __hip_bfloat16 lb = __float2bfloat16(v - hf);
            wD[idx] = *(u16*)&lb;
        }
        return;
    }
    int i1 = idx - WD_N;
    if (i1 < B * HW) {   // transpose interior: x1 -> padded [p][ic] hi/lo
        int p = i1 & (HW - 1);
        int b = i1 >> 14;
        const float* xp = x1 + (size_t)b * C * HW + p;
        bfx8 vh[8], vl[8];
#pragma unroll
        for (int k = 0; k < 8; ++k) {
#pragma unroll
            for (int j = 0; j < 8; ++j) {
                float x = xp[(size_t)(k * 8 + j) * HW];
                __hip_bfloat16 hb = __float2bfloat16(x);
                float hf = __bfloat162float(hb);
                __hip_bfloat16 lb = __float2bfloat16(x - hf);
                vh[k][j] = *(short*)&hb;
                vl[k][j] = *(short*)&lb;
            }
        }
        int dpx = ((p >> 7) + 1) * PW + (p & (W - 1)) + 1;
        u16* dh = x1p_hi + ((size_t)b * PADP + dpx) * C;
        u16* dl = x1p_lo + ((size_t)b * PADP + dpx) * C;
#pragma unroll
        for (int k = 0; k < 8; ++k) {
            *(bfx8*)(dh + k * 8) = vh[k];
            *(bfx8*)(dl + k * 8) = vl[k];
        }
        return;
    }
    int i2 = i1 - B * HW;
    if (i2 < B * PADP) {  // zero the border pixels
        int b2 = i2 / PADP;
        int px = i2 - b2 * PADP;
        int rr = px / PW, cc = px - rr * PW;
        if (rr == 0 || rr == PW - 1 || cc == 0 || cc == PW - 1) {
            u16* zh = x1p_hi + ((size_t)b2 * PADP + px) * C;
            u16* zl = x1p_lo + ((size_t)b2 * PADP + px) * C;
            const bfx8 z = {0, 0, 0, 0, 0, 0, 0, 0};
#pragma unroll
            for (int k = 0; k < 8; ++k) {
                *(bfx8*)(zh + k * 8) = z;
                *(bfx8*)(zl + k * 8) = z;
            }
        }
        return;
    }
    int i3 = i2 - B * PADP;
    if (i3 < WB2_N) {
        // layout: [t 9][chunk 2][nfh 14][lane 64][j 8], wh only
        int step2 = i3 / WB2_STEP;
        int r     = i3 - step2 * WB2_STEP;
        int nfh  = r >> 9;
        int lane = (r >> 3) & 63;
        int j    = r & 7;
        int t = step2 >> 1, chunk = step2 & 1;
        int ic = chunk * 32 + ((lane >> 4) << 3) + j;
        int oc = (nfh << 4) + (lane & 15);
        float v = (oc < OM_C) ? w_om[oc * (C * KK) + ic * KK + t] : 0.0f;
        __hip_bfloat16 hb = __float2bfloat16(v);
        wB2[i3] = *(u16*)&hb;
    }
}

// ---------------- prep2: x0 -> bf16 channel-interleaved, coalesced --------
__global__ void __launch_bounds__(256)
prep2_kernel(const float* __restrict__ x0, u16* __restrict__ x0Tb) {
    int idx = blockIdx.x * 256 + threadIdx.x;   // B*DG*HW = 262144
    int p = idx & (HW - 1);
    int g = (idx >> 14) & (DG - 1);
    int b = idx >> 17;
    const float* src = x0 + ((size_t)(b * C + g * CG) * HW) + p;
    bfx8 v;
#pragma unroll
    for (int c = 0; c < CG; ++c) {
        __hip_bfloat16 hb = __float2bfloat16(src[(size_t)c * HW]);
        v[c] = *(short*)&hb;
    }
    *(bfx8*)(x0Tb + (((size_t)(b * DG + g) * HW + p) << 3)) = v;
}

// ---------------- conv_offset_mask: barrier-free K-loop, direct-global B ---
// 1024 blocks x 256 thr (4 waves = 2 wcol x 2 kidc), 32-px tile -> 4 blk/CU.
// No LDS staging: B-fragments read directly from L2/L3-hot wB2 (coalesced
// 16 B/lane); A flat loads from padded x1p. ZERO barriers in the K-loop ->
// compiler pipelines 9 unrolled taps; cross-block TLP hides latency.
// LDS used only for the one-shot kid-reduction (28,672 B).
__global__ void __launch_bounds__(256, 4)
conv_om_mfma_kernel(const u16* __restrict__ x1p_hi,
                    const u16* __restrict__ x1p_lo,
                    const u16* __restrict__ wB2,
                    const float* __restrict__ b_om,
                    float* __restrict__ rawoff,
                    u16* __restrict__ rawmsk16) {
    __shared__ __align__(16) fx4 red[2][14][64];   // 28,672 B

    int bid  = blockIdx.x;                        // 1024 blocks
    int work = ((bid & 7) << 7) + (bid >> 3);     // XCD-chunked
    int b    = work >> 9;
    int px0  = (work & 511) << 5;                 // 32-px tile

    int tid  = threadIdx.x;
    int lane = tid & 63;
    int wid  = tid >> 6;             // 0..3
    int kidc = wid & 1;              // ic-chunk
    int wcol = wid >> 1;             // 0..1

    fx4 acc[2][7];
#pragma unroll
    for (int mf = 0; mf < 2; ++mf)
#pragma unroll
        for (int nf = 0; nf < 7; ++nf) acc[mf][nf] = fx4{0.f, 0.f, 0.f, 0.f};

    int pA    = px0 + (lane & 15);
    int klane = (lane >> 4) << 3;
    int base0 = (((pA >> 7) + 1) * PW + (pA & (W - 1)) + 1) * C + kidc * 32 + klane;
    int base1 = base0 + 16 * C;      // mf=1 (+16 px, same row)

    const u16* xh_b = x1p_hi + (size_t)b * PADP * C;
    const u16* xl_b = x1p_lo + (size_t)b * PADP * C;
    const u16* wbase = wB2 + kidc * WB2_STEP + ((wcol * 7) << 9) + (lane << 3);

#pragma unroll
    for (int t = 0; t < 9; ++t) {
        int d = TAPD[t];
        bfx8 ah0 = *(const bfx8*)(xh_b + base0 + d);
        bfx8 ah1 = *(const bfx8*)(xh_b + base1 + d);
        bfx8 al0 = *(const bfx8*)(xl_b + base0 + d);
        bfx8 al1 = *(const bfx8*)(xl_b + base1 + d);
        const u16* slab = wbase + (size_t)t * 2 * WB2_STEP;
#pragma unroll
        for (int nf = 0; nf < 7; ++nf) {
            bfx8 bh = *(const bfx8*)(slab + (nf << 9));
            acc[0][nf] = __builtin_amdgcn_mfma_f32_16x16x32_bf16(ah0, bh, acc[0][nf], 0, 0, 0);
            acc[0][nf] = __builtin_amdgcn_mfma_f32_16x16x32_bf16(al0, bh, acc[0][nf], 0, 0, 0);
            acc[1][nf] = __builtin_amdgcn_mfma_f32_16x16x32_bf16(ah1, bh, acc[1][nf], 0, 0, 0);
            acc[1][nf] = __builtin_amdgcn_mfma_f32_16x16x32_bf16(al1, bh, acc[1][nf], 0, 0, 0);
        }
    }

    // kid reduction: kidc=1 waves stash, kidc=0 waves add + epilogue.
    if (kidc) {
#pragma unroll
        for (int mf = 0; mf < 2; ++mf)
#pragma unroll
            for (int nf = 0; nf < 7; ++nf)
                red[wcol][mf * 7 + nf][lane] = acc[mf][nf];
    }
    __syncthreads();
    if (!kidc) {
#pragma unroll
        for (int nf = 0; nf < 7; ++nf) {
#pragma unroll
            for (int mf = 0; mf < 2; ++mf) {
                fx4 v = acc[mf][nf] + red[wcol][mf * 7 + nf][lane];
                int oc  = wcol * 112 + nf * 16 + (lane & 15);
                int pix = px0 + mf * 16 + ((lane >> 4) << 2);
                if (oc < OM_C) {
                    float bb = b_om[oc];
                    if (oc < OFF_C) {
                        float4 r;
                        r.x = v[0] + bb; r.y = v[1] + bb;
                        r.z = v[2] + bb; r.w = v[3] + bb;
                        *(float4*)&rawoff[(size_t)(b * OFF_C + oc) * HW + pix] = r;
                    } else {
                        bfx4 rm;
#pragma unroll
                        for (int q = 0; q < 4; ++q) {
                            __hip_bfloat16 hb = __float2bfloat16(v[q] + bb);
                            rm[q] = *(short*)&hb;
                        }
                        *(bfx4*)&rawmsk16[(size_t)(b * MSK_C + oc - OFF_C) * HW + pix] = rm;
                    }
                }
            }
        }
    }
}

// ---------------- deform conv via MFMA, bf16 gathers (R24 verbatim) --------
__global__ void __launch_bounds__(256, 4)
deform_mfma_kernel(const u16* __restrict__ x0Tb,
                   const float* __restrict__ rawoff,
                   const u16* __restrict__ rawmsk16,
                   const float* __restrict__ pre_offset,
                   const float* __restrict__ pre_sim,
                   const u16* __restrict__ wD,
                   const float* __restrict__ bias,
                   float* __restrict__ out) {
    __shared__ __align__(16) u16 val[2][2][32][VKS];   // 26,624 B

    int bid  = blockIdx.x;                        // 1024 blocks
    int work = ((bid & 7) << 7) + (bid >> 3);     // XCD-chunked
    int b    = work >> 9;
    int px0  = (work & 511) << 5;

    int tid  = threadIdx.x;
    int lane = tid & 63;
    int nf   = tid >> 6;          // wave id = N-frag 0..3

    {
        const bfx8 z = {0, 0, 0, 0, 0, 0, 0, 0};
#pragma unroll
        for (int zz = 0; zz < 2; ++zz) {
            int zc = zz * 256 + tid;           // 0..511
            int sub  = zc & 3;
            int rest = zc >> 2;                // 0..127
            int p    = rest & 31;
            int grel = (rest >> 5) & 1;
            int hl   = rest >> 6;
            *(bfx8*)&val[hl][grel][p][72 + sub * 8] = z;
        }
    }

    fx4 acc[2];
    acc[0] = fx4{0.f, 0.f, 0.f, 0.f};
    acc[1] = fx4{0.f, 0.f, 0.f, 0.f};

    for (int r = 0; r < 4; ++r) {
        __syncthreads();
#pragma unroll
        for (int rep = 0; rep < 3; ++rep) {
            int s = rep * 256 + tid;
            if (s < 576) {
                int p    = s & 31;
                int rest = s >> 5;            // 0..17
                int grel = rest / 9;
                int i    = rest - grel * 9;
                int g    = 2 * r + grel;
                int gi   = g * 9 + i;
                int gp   = px0 + p;
                int h = gp >> 7, w = gp & (W - 1);

                size_t oyi = (size_t)(b * OFF_C + 2 * gi) * HW + gp;
                size_t oxi = (size_t)(b * OFF_C + 2 * gi + 1) * HW + gp;
                size_t mii = (size_t)(b * MSK_C + gi) * HW + gp;
                float offy = MRM * fast_tanh(rawoff[oyi]) + pre_offset[oyi];
                float offx = MRM * fast_tanh(rawoff[oxi]) + pre_offset[oxi];
                float m    = fast_sigmoid(bf2f(rawmsk16[mii]) * pre_sim[mii]);

                float py = offy + (float)(h - 1 + i / 3);
                float px = offx + (float)(w - 1 + i % 3);
                float fy = floorf(py), fx = floorf(px);
                float ly = py - fy, lx = px - fx;
                float hy = 1.0f - ly, hx = 1.0f - lx;
                int y0 = (int)fy, x0i = (int)fx;
                int y1 = y0 + 1, x1i = x0i + 1;
                bool vy0 = (y0 >= 0) && (y0 < H);
                bool vy1 = (y1 >= 0) && (y1 < H);
                bool vx0 = (x0i >= 0) && (x0i < W);
                bool vx1 = (x1i >= 0) && (x1i < W);
                int cy0 = min(max(y0, 0), H - 1), cy1 = min(max(y1, 0), H - 1);
                int cx0 = min(max(x0i, 0), W - 1), cx1 = min(max(x1i, 0), W - 1);
                float w00 = hy * hx * ((vy0 && vx0) ? 1.0f : 0.0f) * m;
                float w01 = hy * lx * ((vy0 && vx1) ? 1.0f : 0.0f) * m;
                float w10 = ly * hx * ((vy1 && vx0) ? 1.0f : 0.0f) * m;
                float w11 = ly * lx * ((vy1 && vx1) ? 1.0f : 0.0f) * m;
                int i00 = cy0 * W + cx0, i01 = cy0 * W + cx1;
                int i10 = cy1 * W + cx0, i11 = cy1 * W + cx1;

                const u16* xg = x0Tb + (((size_t)(b * DG + g) * HW) << 3);
                bfx8 c00 = *(const bfx8*)(xg + ((size_t)i00 << 3));
                bfx8 c01 = *(const bfx8*)(xg + ((size_t)i01 << 3));
                bfx8 c10 = *(const bfx8*)(xg + ((size_t)i10 << 3));
                bfx8 c11 = *(const bfx8*)(xg + ((size_t)i11 << 3));

                float v[CG];
#pragma unroll
                for (int c = 0; c < CG; ++c) {
                    v[c] = w00 * bf2f((u16)c00[c]) + w01 * bf2f((u16)c01[c])
                         + w10 * bf2f((u16)c10[c]) + w11 * bf2f((u16)c11[c]);
                }

                bfx8 vh, vl;
#pragma unroll
                for (int c = 0; c < CG; ++c) {
                    __hip_bfloat16 hb = __float2bfloat16(v[c]);
                    float hf = __bfloat162float(hb);
                    __hip_bfloat16 lb = __float2bfloat16(v[c] - hf);
                    vh[c] = *(short*)&hb;
                    vl[c] = *(short*)&lb;
                }
                *(bfx8*)&val[0][grel][p][i * 8] = vh;
                *(bfx8*)&val[1][grel][p][i * 8] = vl;
            }
        }
        __syncthreads();
#pragma unroll
        for (int ks = 0; ks < 6; ++ks) {
            int grel = ks / 3;
            int ksl  = ks - grel * 3;
            int g    = 2 * r + grel;
            int kk   = ksl * 32 + ((lane >> 4) << 3);

            const u16* bp = wD + (size_t)(((g * 3 + ksl) * 4 + nf) * 2) * 512 + lane * 8;
            bfx8 bh = *(const bfx8*)bp;
            bfx8 bl = *(const bfx8*)(bp + 512);

            int row0 = lane & 15;
            bfx8 a0h = *(const bfx8*)&val[0][grel][row0][kk];
            bfx8 a0l = *(const bfx8*)&val[1][grel][row0][kk];
            bfx8 a1h = *(const bfx8*)&val[0][grel][row0 + 16][kk];
            bfx8 a1l = *(const bfx8*)&val[1][grel][row0 + 16][kk];

            acc[0] = __builtin_amdgcn_mfma_f32_16x16x32_bf16(a0h, bh, acc[0], 0, 0, 0);
            acc[0] = __builtin_amdgcn_mfma_f32_16x16x32_bf16(a0l, bh, acc[0], 0, 0, 0);
            acc[0] = __builtin_amdgcn_mfma_f32_16x16x32_bf16(a0h, bl, acc[0], 0, 0, 0);
            acc[1] = __builtin_amdgcn_mfma_f32_16x16x32_bf16(a1h, bh, acc[1], 0, 0, 0);
            acc[1] = __builtin_amdgcn_mfma_f32_16x16x32_bf16(a1l, bh, acc[1], 0, 0, 0);
            acc[1] = __builtin_amdgcn_mfma_f32_16x16x32_bf16(a1h, bl, acc[1], 0, 0, 0);
        }
    }

    __syncthreads();
    float* trans = (float*)&val[0][0][0][0];   // 64*36*4 = 9216 B
#pragma unroll
    for (int t = 0; t < 2; ++t) {
        int oc = nf * 16 + (lane & 15);
        int p4 = t * 16 + ((lane >> 4) << 2);
        *(fx4*)&trans[oc * 36 + p4] = acc[t];
    }
    __syncthreads();
#pragma unroll
    for (int t = 0; t < 2; ++t) {
        int f  = t * 256 + tid;           // 0..511
        int oc = f >> 3;                  // 0..63
        int c4 = f & 7;
        float4 v = *(float4*)&trans[oc * 36 + c4 * 4];
        float bb = bias[oc];
        v.x += bb; v.y += bb; v.z += bb; v.w += bb;
        *(float4*)&out[((size_t)b * O + oc) * HW + px0 + c4 * 4] = v;
    }
}

// ---------------- Launch ----------------
extern "C" void kernel_launch(void* const* d_in, const int* in_sizes, int n_in,
                              void* d_out, int out_size, void* d_ws, size_t ws_size,
                              hipStream_t stream) {
    (void)in_sizes; (void)n_in; (void)out_size; (void)ws_size;
    const float* x0         = (const float*)d_in[0];
    const float* x1         = (const float*)d_in[1];
    const float* pre_offset = (const float*)d_in[2];
    const float* pre_sim    = (const float*)d_in[3];
    const float* weight     = (const float*)d_in[4];
    const float* bias       = (const float*)d_in[5];
    const float* w_om       = (const float*)d_in[6];
    const float* b_om       = (const float*)d_in[7];
    float* out = (float*)d_out;

    // ws layout: rawoff(f32) | rawmsk(bf16) | xbuf(x1p_hi,x1p_lo / x0Tb) | wB2 | wD
    float* rawoff   = (float*)d_ws;                       // B*OFF_C*HW floats
    u16*   rawmsk16 = (u16*)(rawoff + (size_t)B * OFF_C * HW);  // B*MSK_C*HW u16
    u16*   xbuf     = rawmsk16 + (size_t)B * MSK_C * HW;
    u16*   x1p_hi = xbuf;                               // X1P_N u16
    u16*   x1p_lo = x1p_hi + (size_t)X1P_N;             // X1P_N u16
    u16*   x0Tb   = xbuf;                               // aliases x1p (after conv)
    u16*   wB2    = x1p_lo + (size_t)X1P_N;             // WB2_N u16
    u16*   wD     = wB2 + (size_t)WB2_N;                // WD_N u16

    {
        int total = WD_N + B * HW + B * PADP + WB2_N;   // 293896
        prep1_kernel<<<(total + 255) / 256, 256, 0, stream>>>(
            weight, w_om, x1, wD, x1p_hi, x1p_lo, wB2);
    }
    {
        conv_om_mfma_kernel<<<1024, 256, 0, stream>>>(
            x1p_hi, x1p_lo, wB2, b_om, rawoff, rawmsk16);
    }
    {
        prep2_kernel<<<(B * DG * HW) / 256, 256, 0, stream>>>(x0, x0Tb);
    }
    {
        deform_mfma_kernel<<<1024, 256, 0, stream>>>(
            x0Tb, rawoff, rawmsk16, pre_offset, pre_sim, wD, bias, out);
    }
}